// Round 1
// baseline (412.066 us; speedup 1.0000x reference)
//
#include <hip/hip_runtime.h>
#include <hip/hip_bf16.h>
#include <stdint.h>
#include <string.h>

#define D_MODEL 768
#define H_HEADS 12
#define HD_ 64
#define N_QKV 2304

typedef __bf16 bf16x8 __attribute__((ext_vector_type(8)));
typedef float f32x4 __attribute__((ext_vector_type(4)));

__device__ __forceinline__ unsigned short f2bfbits(float f) {
  union { float f; unsigned u; } x; x.f = f;
  unsigned r = x.u + 0x7fffu + ((x.u >> 16) & 1u);
  return (unsigned short)(r >> 16);
}

// pack two non-negative floats to bf16 pair
__device__ __forceinline__ unsigned pk2(float a, float b) {
  union { float f; unsigned u; } x, y; x.f = a; y.f = b;
  return ((x.u + 0x8000u) >> 16) | ((y.u + 0x8000u) & 0xffff0000u);
}

// async global->LDS, 16B per lane; LDS dest = wave-uniform base + lane*16
__device__ __forceinline__ void gload_lds16(const void* g, void* l) {
  __builtin_amdgcn_global_load_lds(
      (const __attribute__((address_space(1))) unsigned int*)g,
      (__attribute__((address_space(3))) unsigned int*)l, 16, 0, 0);
}

// ---------------- weight transpose + fp32->bf16 ----------------
__global__ void transpose_w(const float* __restrict__ in, unsigned short* __restrict__ out,
                            int R, int C) {
  __shared__ float tile[32][33];
  int c0 = blockIdx.x * 32, r0 = blockIdx.y * 32;
  int tx = threadIdx.x, ty = threadIdx.y;
#pragma unroll
  for (int i = 0; i < 32; i += 8)
    tile[ty + i][tx] = in[(size_t)(r0 + ty + i) * C + c0 + tx];
  __syncthreads();
#pragma unroll
  for (int i = 0; i < 32; i += 8)
    out[(size_t)(c0 + ty + i) * R + r0 + tx] = f2bfbits(tile[tx][ty + i]);
}

// ---------------- V transpose with per-64-token key permute ----------------
__global__ void transpose_v(const unsigned short* __restrict__ qkv,
                            unsigned short* __restrict__ vT, int M) {
  __shared__ unsigned short tile[32][33];
  int t0 = blockIdx.x * 32, c0 = blockIdx.y * 32;
  int tx = threadIdx.x, ty = threadIdx.y;
#pragma unroll
  for (int i = 0; i < 32; i += 8)
    tile[ty + i][tx] = qkv[(size_t)(t0 + ty + i) * N_QKV + 1536 + c0 + tx];
  __syncthreads();
  int t = t0 + tx;
  int c = t & 63;
  int kp = ((c >> 5) << 5) | (((c >> 2) & 3) << 3) | (((c >> 4) & 1) << 2) | (c & 3);
  size_t col = (size_t)(t & ~63) + kp;
#pragma unroll
  for (int i = 0; i < 32; i += 8)
    vT[(size_t)(c0 + ty + i) * M + col] = tile[tx][ty + i];
}

// ---------------- layernorm -> bf16 ----------------
__global__ void ln_bf16(const float* __restrict__ x, const float* __restrict__ g,
                        const float* __restrict__ be, unsigned short* __restrict__ out) {
  int row = blockIdx.x;
  const float* xr = x + (size_t)row * D_MODEL;
  int t = threadIdx.x;
  float v0 = xr[t], v1 = xr[t + 256], v2 = xr[t + 512];
  float s = v0 + v1 + v2;
  float s2 = v0 * v0 + v1 * v1 + v2 * v2;
#pragma unroll
  for (int off = 32; off > 0; off >>= 1) {
    s += __shfl_down(s, off, 64);
    s2 += __shfl_down(s2, off, 64);
  }
  __shared__ float red[8];
  int w = t >> 6, lane = t & 63;
  if (lane == 0) { red[w] = s; red[w + 4] = s2; }
  __syncthreads();
  if (t == 0) {
    float a = red[0] + red[1] + red[2] + red[3];
    float b = red[4] + red[5] + red[6] + red[7];
    red[0] = a * (1.0f / 768.0f);
    red[4] = b * (1.0f / 768.0f);
  }
  __syncthreads();
  float mu = red[0];
  float var = red[4] - mu * mu;
  float rs = rsqrtf(var + 1e-6f);
  unsigned short* orow = out + (size_t)row * D_MODEL;
  orow[t]       = f2bfbits((v0 - mu) * rs * g[t]       + be[t]);
  orow[t + 256] = f2bfbits((v1 - mu) * rs * g[t + 256] + be[t + 256]);
  orow[t + 512] = f2bfbits((v2 - mu) * rs * g[t + 512] + be[t + 512]);
}

// ---------------- bf16 MFMA GEMM v6 (kept for N=768 GEMMs: Wo, FC2) ----------
template <int EPI>
__global__ void __launch_bounds__(256, 3)
gemm_rs(const unsigned short* __restrict__ A,
        const unsigned short* __restrict__ Bt,
        const float* __restrict__ bias,
        const float* __restrict__ res,
        void* __restrict__ outv,
        int M, int N, int K) {
  __shared__ unsigned short lA[2][128 * 32];
  __shared__ unsigned short lB[2][128 * 32];
  int tid = threadIdx.x;
  int w = tid >> 6, lane = tid & 63;
  int id = blockIdx.x;
  int nn = N >> 7, bandM = (M >> 7) >> 3;
  int xcd = id & 7, s = id >> 3;
  int mt = xcd * bandM + s / nn;
  int nt = s - (s / nn) * nn;
  int m0 = mt * 128, n0 = nt * 128;
  int wm = (w >> 1) * 64, wn = (w & 1) * 64;
  f32x4 acc[4][4];
#pragma unroll
  for (int i = 0; i < 4; i++)
#pragma unroll
    for (int j = 0; j < 4; j++) acc[i][j] = (f32x4){0.f, 0.f, 0.f, 0.f};

  int sr = tid >> 2, sc = tid & 3;
  const unsigned short* gA = A + (size_t)(m0 + sr) * K + sc * 8;
  const unsigned short* gB = Bt + (size_t)(n0 + sr) * K + sc * 8;
  int wOff = sr * 64 + ((((sr >> 1) & 3) ^ sc) * 16);
  int fm = lane & 15, fg = lane >> 4;

  uint4 pA0, pA1, pB0, pB1;
  uint4 qA0, qA1, qB0, qB1;

  int nk = K >> 5;
  pA0 = *(const uint4*)(gA);
  pA1 = *(const uint4*)(gA + (size_t)64 * K);
  pB0 = *(const uint4*)(gB);
  pB1 = *(const uint4*)(gB + (size_t)64 * K);
  qA0 = *(const uint4*)(gA + 32);
  qA1 = *(const uint4*)(gA + (size_t)64 * K + 32);
  qB0 = *(const uint4*)(gB + 32);
  qB1 = *(const uint4*)(gB + (size_t)64 * K + 32);

  for (int k = 0; k < nk; k += 2) {
    {
      char* la = (char*)&lA[0][0];
      char* lb = (char*)&lB[0][0];
      *(uint4*)(la + wOff) = pA0;
      *(uint4*)(la + wOff + 4096) = pA1;
      *(uint4*)(lb + wOff) = pB0;
      *(uint4*)(lb + wOff + 4096) = pB1;
      if (k + 2 < nk) {
        int k0 = (k + 2) * 32;
        pA0 = *(const uint4*)(gA + k0);
        pA1 = *(const uint4*)(gA + (size_t)64 * K + k0);
        pB0 = *(const uint4*)(gB + k0);
        pB1 = *(const uint4*)(gB + (size_t)64 * K + k0);
      }
      asm volatile("s_waitcnt lgkmcnt(0)\ns_barrier" ::: "memory");
      bf16x8 af[4], bfr[4];
#pragma unroll
      for (int i = 0; i < 4; i++) {
        int rr = wm + i * 16 + fm;
        af[i] = *(const bf16x8*)(la + rr * 64 + ((((rr >> 1) & 3) ^ fg) * 16));
      }
#pragma unroll
      for (int j = 0; j < 4; j++) {
        int rr = wn + j * 16 + fm;
        bfr[j] = *(const bf16x8*)(lb + rr * 64 + ((((rr >> 1) & 3) ^ fg) * 16));
      }
#pragma unroll
      for (int i = 0; i < 4; i++)
#pragma unroll
        for (int j = 0; j < 4; j++)
          acc[i][j] = __builtin_amdgcn_mfma_f32_16x16x32_bf16(af[i], bfr[j], acc[i][j], 0, 0, 0);
    }
    {
      char* la = (char*)&lA[1][0];
      char* lb = (char*)&lB[1][0];
      *(uint4*)(la + wOff) = qA0;
      *(uint4*)(la + wOff + 4096) = qA1;
      *(uint4*)(lb + wOff) = qB0;
      *(uint4*)(lb + wOff + 4096) = qB1;
      if (k + 3 < nk) {
        int k0 = (k + 3) * 32;
        qA0 = *(const uint4*)(gA + k0);
        qA1 = *(const uint4*)(gA + (size_t)64 * K + k0);
        qB0 = *(const uint4*)(gB + k0);
        qB1 = *(const uint4*)(gB + (size_t)64 * K + k0);
      }
      asm volatile("s_waitcnt lgkmcnt(0)\ns_barrier" ::: "memory");
      bf16x8 af[4], bfr[4];
#pragma unroll
      for (int i = 0; i < 4; i++) {
        int rr = wm + i * 16 + fm;
        af[i] = *(const bf16x8*)(la + rr * 64 + ((((rr >> 1) & 3) ^ fg) * 16));
      }
#pragma unroll
      for (int j = 0; j < 4; j++) {
        int rr = wn + j * 16 + fm;
        bfr[j] = *(const bf16x8*)(lb + rr * 64 + ((((rr >> 1) & 3) ^ fg) * 16));
      }
#pragma unroll
      for (int i = 0; i < 4; i++)
#pragma unroll
        for (int j = 0; j < 4; j++)
          acc[i][j] = __builtin_amdgcn_mfma_f32_16x16x32_bf16(af[i], bfr[j], acc[i][j], 0, 0, 0);
    }
  }

  int er = (lane >> 4) * 4, ec = lane & 15;
#pragma unroll
  for (int i = 0; i < 4; i++) {
#pragma unroll
    for (int j = 0; j < 4; j++) {
      int n = n0 + wn + j * 16 + ec;
      float bv = bias[n];
#pragma unroll
      for (int r = 0; r < 4; r++) {
        int m = m0 + wm + i * 16 + er + r;
        float v = acc[i][j][r] + bv;
        if (EPI == 1) {
          v += res[(size_t)m * N + n];
          ((float*)outv)[(size_t)m * N + n] = v;
        } else {
          if (EPI == 2) v = 0.5f * v * (1.0f + erff(v * 0.70710678118f));
          ((unsigned short*)outv)[(size_t)m * N + n] = f2bfbits(v);
        }
      }
    }
  }
}

// ---------------- 256x256 8-phase GEMM (T2+T3+T4+T5, m201 template) ---------
// BM=BN=256, BK=64, 512 thr (8 waves, 2M x 4N), LDS 128 KiB (2 dbuf x 2 ks x
// (A+B) x 256x32 bf16). Staging via global_load_lds w/ pre-swizzled global
// source (linear LDS dest). Counted vmcnt(6) once per K-tile; never drained
// to 0 in the loop. Half-tile stage order per tile t:
//   p1: A-ks1(t+1)  p2: B-ks0(t+2)  p3: B-ks1(t+2)  p4: A-ks0(t+2)
// WAR-safe: each target slot's last LDS read is >=1 barrier-pair earlier
// (B frags for both ks are register-held from p1; A-ks0 last read p2;
//  A-ks1 last read p4 of previous tile).
#define BAR_() asm volatile("s_barrier" ::: "memory")
#define BARLGKM_() asm volatile("s_barrier\ns_waitcnt lgkmcnt(0)" ::: "memory")

template <int EPI>
__global__ void __launch_bounds__(512, 2)
gemm256(const unsigned short* __restrict__ A,
        const unsigned short* __restrict__ Bt,
        const float* __restrict__ bias,
        void* __restrict__ outv,
        int M, int N, int K) {
  __shared__ unsigned short sA[2][2][256 * 32];
  __shared__ unsigned short sB[2][2][256 * 32];
  const int tid = threadIdx.x;
  const int w = tid >> 6, lane = tid & 63;
  const int fm = lane & 15, fg = lane >> 4;

  const int id = blockIdx.x;
  const int nn = N >> 8, bandM = (M >> 8) >> 3;
  const int xcd = id & 7, sblk = id >> 3;
  const int mt = xcd * bandM + sblk / nn;
  const int nt = sblk - (sblk / nn) * nn;
  const int m0 = mt << 8, n0 = nt << 8;
  const int wm = (w >> 2) * 128, wn = (w & 3) * 64;

  f32x4 acc[8][4];
#pragma unroll
  for (int i = 0; i < 8; ++i)
#pragma unroll
    for (int j = 0; j < 4; ++j) acc[i][j] = (f32x4){0.f, 0.f, 0.f, 0.f};

  // loop-invariant ds_read byte offsets within one [256 x 32elem] ks-region
  int offA0[4], offA1[4], offB[4];
#pragma unroll
  for (int i = 0; i < 4; ++i) {
    int ra = wm + i * 16 + fm;
    offA0[i] = ra * 64 + ((((ra >> 1) & 3) ^ fg) * 16);
    int rb = wm + 64 + i * 16 + fm;
    offA1[i] = rb * 64 + ((((rb >> 1) & 3) ^ fg) * 16);
    int rc = wn + i * 16 + fm;
    offB[i] = rc * 64 + ((((rc >> 1) & 3) ^ fg) * 16);
  }

  // staging: lane l of wave w, call c -> linear LDS (w*2+c)*1024 + l*16
  // = row r=(w*2+c)*16 + l/4, slot s=l&3; data chunk cg = s ^ ((r>>1)&3)
  const int r0 = w * 32 + (lane >> 2);
  const int cg = (lane & 3) ^ ((r0 >> 1) & 3);   // same for r0 and r0+16
  const unsigned short* gA0 = A + (size_t)(m0 + r0) * K + cg * 8;
  const unsigned short* gA1 = gA0 + (size_t)16 * K;
  const unsigned short* gB0 = Bt + (size_t)(n0 + r0) * K + cg * 8;
  const unsigned short* gB1 = gB0 + (size_t)16 * K;
  const int lo0 = w * 2048, lo1 = w * 2048 + 1024;
  const int NT = K >> 6;

  auto stA = [&](int kt, int ks, int buf) {
    int kk = kt < NT ? kt : NT - 1;     // clamp: uniform vmcnt accounting
    int off = kk * 64 + ks * 32;
    char* base = (char*)&sA[buf][ks][0];
    gload_lds16(gA0 + off, base + lo0);
    gload_lds16(gA1 + off, base + lo1);
  };
  auto stB = [&](int kt, int ks, int buf) {
    int kk = kt < NT ? kt : NT - 1;
    int off = kk * 64 + ks * 32;
    char* base = (char*)&sB[buf][ks][0];
    gload_lds16(gB0 + off, base + lo0);
    gload_lds16(gB1 + off, base + lo1);
  };

  // prologue: tile0 fully, then tile1 {B0,B1,A0}; 6 loads left in flight
  stB(0, 0, 0); stB(0, 1, 0); stA(0, 0, 0); stA(0, 1, 0);
  asm volatile("s_waitcnt vmcnt(4)" ::: "memory");
  stB(1, 0, 1); stB(1, 1, 1); stA(1, 0, 1);
  asm volatile("s_waitcnt vmcnt(6)" ::: "memory");
  BAR_();

  for (int t = 0; t < NT; ++t) {
    const int cur = t & 1;
    const char* As0 = (const char*)&sA[cur][0][0];
    const char* As1 = (const char*)&sA[cur][1][0];
    const char* Bs0 = (const char*)&sB[cur][0][0];
    const char* Bs1 = (const char*)&sB[cur][1][0];
    bf16x8 a[4], b0[4], b1[4];

    // ---- phase 1: (qm0, ks0); load B frags for both ks; stage A-ks1(t+1)
#pragma unroll
    for (int i = 0; i < 4; ++i) a[i] = *(const bf16x8*)(As0 + offA0[i]);
#pragma unroll
    for (int j = 0; j < 4; ++j) b0[j] = *(const bf16x8*)(Bs0 + offB[j]);
#pragma unroll
    for (int j = 0; j < 4; ++j) b1[j] = *(const bf16x8*)(Bs1 + offB[j]);
    stA(t + 1, 1, (t + 1) & 1);
    BARLGKM_();
    __builtin_amdgcn_s_setprio(1);
#pragma unroll
    for (int i = 0; i < 4; ++i)
#pragma unroll
      for (int j = 0; j < 4; ++j)
        acc[i][j] = __builtin_amdgcn_mfma_f32_16x16x32_bf16(a[i], b0[j], acc[i][j], 0, 0, 0);
    __builtin_amdgcn_s_setprio(0);
    BAR_();

    // ---- phase 2: (qm1, ks0); stage B-ks0(t+2)
#pragma unroll
    for (int i = 0; i < 4; ++i) a[i] = *(const bf16x8*)(As0 + offA1[i]);
    stB(t + 2, 0, cur);
    BARLGKM_();
    __builtin_amdgcn_s_setprio(1);
#pragma unroll
    for (int i = 0; i < 4; ++i)
#pragma unroll
      for (int j = 0; j < 4; ++j)
        acc[4 + i][j] = __builtin_amdgcn_mfma_f32_16x16x32_bf16(a[i], b0[j], acc[4 + i][j], 0, 0, 0);
    __builtin_amdgcn_s_setprio(0);
    BAR_();

    // ---- phase 3: (qm0, ks1); stage B-ks1(t+2)
#pragma unroll
    for (int i = 0; i < 4; ++i) a[i] = *(const bf16x8*)(As1 + offA0[i]);
    stB(t + 2, 1, cur);
    BARLGKM_();
    __builtin_amdgcn_s_setprio(1);
#pragma unroll
    for (int i = 0; i < 4; ++i)
#pragma unroll
      for (int j = 0; j < 4; ++j)
        acc[i][j] = __builtin_amdgcn_mfma_f32_16x16x32_bf16(a[i], b1[j], acc[i][j], 0, 0, 0);
    __builtin_amdgcn_s_setprio(0);
    BAR_();

    // ---- phase 4: (qm1, ks1); stage A-ks0(t+2); counted drain vmcnt(6)
#pragma unroll
    for (int i = 0; i < 4; ++i) a[i] = *(const bf16x8*)(As1 + offA1[i]);
    stA(t + 2, 0, cur);
    asm volatile("s_waitcnt vmcnt(6)" ::: "memory");
    BARLGKM_();
    __builtin_amdgcn_s_setprio(1);
#pragma unroll
    for (int i = 0; i < 4; ++i)
#pragma unroll
      for (int j = 0; j < 4; ++j)
        acc[4 + i][j] = __builtin_amdgcn_mfma_f32_16x16x32_bf16(a[i], b1[j], acc[4 + i][j], 0, 0, 0);
    __builtin_amdgcn_s_setprio(0);
    BAR_();
  }

  // drain remaining async LDS-DMA before the workgroup can exit
  asm volatile("s_waitcnt vmcnt(0)" ::: "memory");

  const int er = fg * 4, ec = fm;
#pragma unroll
  for (int i = 0; i < 8; ++i) {
#pragma unroll
    for (int j = 0; j < 4; ++j) {
      int n = n0 + wn + j * 16 + ec;
      float bv = bias[n];
#pragma unroll
      for (int r = 0; r < 4; ++r) {
        int m = m0 + wm + i * 16 + er + r;
        float v = acc[i][j][r] + bv;
        if (EPI == 2) v = 0.5f * v * (1.0f + erff(v * 0.70710678118f));
        ((unsigned short*)outv)[(size_t)m * N + n] = f2bfbits(v);
      }
    }
  }
}

// ---------------- ragged flash attention v4 ---------------------------------
__global__ void attn_flash4(const unsigned short* __restrict__ qkv,
                            const unsigned short* __restrict__ vT,
                            const int* __restrict__ cu,
                            unsigned short* __restrict__ out, int M) {
  int id = blockIdx.x;
  int qc = id / 96;
  int bh = id - qc * 96;
  int b = bh / 12, h = bh - b * 12;
  int tok0 = cu[b];
  int len = cu[b + 1] - tok0;
  if (qc * 128 >= len) return;

  __shared__ unsigned short lK[2][64 * 64];
  __shared__ unsigned short lVT[2][64 * 64];

  int tid = threadIdx.x, w = tid >> 6, lane = tid & 63;
  int fm = lane & 15, fg = lane >> 4;
  int xm = fm & 7;
  int qbase = qc * 128 + w * 32;

  bf16x8 qf[2][2];
#pragma unroll
  for (int qs = 0; qs < 2; qs++)
#pragma unroll
    for (int kh = 0; kh < 2; kh++)
      qf[qs][kh] = *(const bf16x8*)(qkv + (size_t)(tok0 + qbase + qs * 16 + fm) * N_QKV +
                                    h * 64 + kh * 32 + fg * 8);

  f32x4 Oacc[2][4];
#pragma unroll
  for (int qs = 0; qs < 2; qs++)
#pragma unroll
    for (int dt = 0; dt < 4; dt++) Oacc[qs][dt] = (f32x4){0.f, 0.f, 0.f, 0.f};
  float lrow[2] = {0.f, 0.f};
  const float C2 = 0.18033688011112042f;  // log2(e)/sqrt(64)

  int sr = tid >> 3, sp = tid & 7, sl = sp ^ (sr & 7);
  const unsigned short* kg0 = qkv + D_MODEL + h * 64 + sl * 8;
  const unsigned short* vg0 = vT + (size_t)(h * 64 + sr) * M + tok0 + sl * 8;

  uint4 rk0, rk1, rv0, rv1;
  auto gload = [&](int kt) {
    rk0 = *(const uint4*)(kg0 + (size_t)(tok0 + kt + sr) * N_QKV);
    rk1 = *(const uint4*)(kg0 + (size_t)(tok0 + kt + sr + 32) * N_QKV);
    rv0 = *(const uint4*)(vg0 + kt);
    rv1 = *(const uint4*)(vg0 + (size_t)32 * M + kt);
  };

  int nkt = len >> 6;
  gload(0);
  for (int kt = 0; kt < nkt; kt++) {
    int cur = kt & 1;
    *(uint4*)((char*)&lK[cur][0] + tid * 16) = rk0;
    *(uint4*)((char*)&lK[cur][0] + tid * 16 + 4096) = rk1;
    *(uint4*)((char*)&lVT[cur][0] + tid * 16) = rv0;
    *(uint4*)((char*)&lVT[cur][0] + tid * 16 + 4096) = rv1;
    if (kt + 1 < nkt) gload((kt + 1) * 64);
    asm volatile("s_waitcnt lgkmcnt(0)\ns_barrier" ::: "memory");

    f32x4 s[2][4];
#pragma unroll
    for (int qs = 0; qs < 2; qs++)
#pragma unroll
      for (int t = 0; t < 4; t++) s[qs][t] = (f32x4){0.f, 0.f, 0.f, 0.f};
#pragma unroll
    for (int t = 0; t < 4; t++) {
      bf16x8 kf0 = *(const bf16x8*)&lK[cur][(t * 16 + fm) * 64 + ((fg ^ xm) * 8)];
      bf16x8 kf1 = *(const bf16x8*)&lK[cur][(t * 16 + fm) * 64 + (((4 + fg) ^ xm) * 8)];
#pragma unroll
      for (int qs = 0; qs < 2; qs++) {
        s[qs][t] = __builtin_amdgcn_mfma_f32_16x16x32_bf16(kf0, qf[qs][0], s[qs][t], 0, 0, 0);
        s[qs][t] = __builtin_amdgcn_mfma_f32_16x16x32_bf16(kf1, qf[qs][1], s[qs][t], 0, 0, 0);
      }
    }

    union { bf16x8 v; unsigned u[4]; } af[2][2];
#pragma unroll
    for (int qs = 0; qs < 2; qs++) {
      float ssum = 0.f;
#pragma unroll
      for (int t = 0; t < 4; t++) {
#pragma unroll
        for (int r = 0; r < 4; r++) {
          float p = exp2f(s[qs][t][r] * C2);
          s[qs][t][r] = p;
          ssum += p;
        }
      }
      lrow[qs] += ssum;
      af[qs][0].u[0] = pk2(s[qs][0][0], s[qs][0][1]);
      af[qs][0].u[1] = pk2(s[qs][0][2], s[qs][0][3]);
      af[qs][0].u[2] = pk2(s[qs][1][0], s[qs][1][1]);
      af[qs][0].u[3] = pk2(s[qs][1][2], s[qs][1][3]);
      af[qs][1].u[0] = pk2(s[qs][2][0], s[qs][2][1]);
      af[qs][1].u[1] = pk2(s[qs][2][2], s[qs][2][3]);
      af[qs][1].u[2] = pk2(s[qs][3][0], s[qs][3][1]);
      af[qs][1].u[3] = pk2(s[qs][3][2], s[qs][3][3]);
    }

#pragma unroll
    for (int dt = 0; dt < 4; dt++) {
      bf16x8 vf0 = *(const bf16x8*)&lVT[cur][(dt * 16 + fm) * 64 + ((fg ^ xm) * 8)];
      bf16x8 vf1 = *(const bf16x8*)&lVT[cur][(dt * 16 + fm) * 64 + (((4 + fg) ^ xm) * 8)];
#pragma unroll
      for (int qs = 0; qs < 2; qs++) {
        Oacc[qs][dt] = __builtin_amdgcn_mfma_f32_16x16x32_bf16(af[qs][0].v, vf0, Oacc[qs][dt], 0, 0, 0);
        Oacc[qs][dt] = __builtin_amdgcn_mfma_f32_16x16x32_bf16(af[qs][1].v, vf1, Oacc[qs][dt], 0, 0, 0);
      }
    }
  }

#pragma unroll
  for (int qs = 0; qs < 2; qs++) {
    lrow[qs] += __shfl_xor(lrow[qs], 16, 64);
    lrow[qs] += __shfl_xor(lrow[qs], 32, 64);
    float inv = 1.0f / lrow[qs];
    float ir[4];
#pragma unroll
    for (int r = 0; r < 4; r++) ir[r] = __shfl(inv, fg * 4 + r, 64);
#pragma unroll
    for (int dt = 0; dt < 4; dt++)
#pragma unroll
      for (int r = 0; r < 4; r++)
        out[(size_t)(tok0 + qbase + qs * 16 + fg * 4 + r) * D_MODEL + h * 64 + dt * 16 + fm] =
            f2bfbits(Oacc[qs][dt][r] * ir[r]);
  }
}

extern "C" void kernel_launch(void* const* d_in, const int* in_sizes, int n_in,
                              void* d_out, int out_size, void* d_ws, size_t ws_size,
                              hipStream_t stream) {
  const float* x    = (const float*)d_in[0];
  const int* cu     = (const int*)d_in[1];
  const float* g1   = (const float*)d_in[2];
  const float* be1  = (const float*)d_in[3];
  const float* Wqkv = (const float*)d_in[4];
  const float* bqkv = (const float*)d_in[5];
  const float* Wo   = (const float*)d_in[6];
  const float* bo   = (const float*)d_in[7];
  const float* g2   = (const float*)d_in[8];
  const float* be2  = (const float*)d_in[9];
  const float* W1   = (const float*)d_in[10];
  const float* bfc1 = (const float*)d_in[11];
  const float* W2   = (const float*)d_in[12];
  const float* bfc2 = (const float*)d_in[13];
  float* out = (float*)d_out;
  int M = in_sizes[0] / D_MODEL;  // 6144

  unsigned short* WqkvT = (unsigned short*)d_ws;                       // 2304x768
  unsigned short* WoT   = WqkvT + 2304 * 768;                          // 768x768
  unsigned short* W1T   = WoT + 768 * 768;                             // 3072x768
  unsigned short* W2T   = W1T + 3072 * 768;                            // 768x3072
  unsigned short* bufA  = W2T + 768 * 3072;                            // M x 768 bf16
  float* x1             = (float*)(bufA + (size_t)M * D_MODEL);        // M x 768 f32
  unsigned short* qkvb  = (unsigned short*)(x1 + (size_t)M * D_MODEL); // M x 3072 bf16
  unsigned short* vT = (unsigned short*)x1;  // overlaps x1 (dead before Wo-gemm)

  dim3 b32(32, 8);
  transpose_w<<<dim3(2304 / 32, 768 / 32), b32, 0, stream>>>(Wqkv, WqkvT, 768, 2304);
  transpose_w<<<dim3(768 / 32, 768 / 32), b32, 0, stream>>>(Wo, WoT, 768, 768);
  transpose_w<<<dim3(3072 / 32, 768 / 32), b32, 0, stream>>>(W1, W1T, 768, 3072);
  transpose_w<<<dim3(768 / 32, 3072 / 32), b32, 0, stream>>>(W2, W2T, 3072, 768);

  ln_bf16<<<M, 256, 0, stream>>>(x, g1, be1, bufA);
  gemm256<0><<<(2304 / 256) * (M / 256), 512, 0, stream>>>(bufA, WqkvT, bqkv, qkvb, M, 2304, 768);
  transpose_v<<<dim3(M / 32, 768 / 32), b32, 0, stream>>>(qkvb, vT, M);
  attn_flash4<<<8 * 96, 256, 0, stream>>>(qkvb, vT, cu, bufA, M);
  gemm_rs<1><<<(768 / 128) * (M / 128), 256, 0, stream>>>(bufA, WoT, bo, x, x1, M, 768, 768);
  ln_bf16<<<M, 256, 0, stream>>>(x1, g2, be2, bufA);
  gemm256<2><<<(3072 / 256) * (M / 256), 512, 0, stream>>>(bufA, W1T, bfc1, qkvb, M, 3072, 768);
  gemm_rs<1><<<(768 / 128) * (M / 128), 256, 0, stream>>>(qkvb, W2T, bfc2, x1, out, M, 768, 3072);
}

// Round 2
// 380.939 us; speedup vs baseline: 1.0817x; 1.0817x over previous
//
#include <hip/hip_runtime.h>
#include <hip/hip_bf16.h>
#include <stdint.h>
#include <string.h>

#define D_MODEL 768
#define H_HEADS 12
#define HD_ 64
#define N_QKV 2304

typedef __bf16 bf16x8 __attribute__((ext_vector_type(8)));
typedef float f32x4 __attribute__((ext_vector_type(4)));

__device__ __forceinline__ unsigned short f2bfbits(float f) {
  union { float f; unsigned u; } x; x.f = f;
  unsigned r = x.u + 0x7fffu + ((x.u >> 16) & 1u);
  return (unsigned short)(r >> 16);
}

// pack two non-negative floats to bf16 pair
__device__ __forceinline__ unsigned pk2(float a, float b) {
  union { float f; unsigned u; } x, y; x.f = a; y.f = b;
  return ((x.u + 0x8000u) >> 16) | ((y.u + 0x8000u) & 0xffff0000u);
}

// async global->LDS, 16B per lane; LDS dest = wave-uniform base + lane*16
__device__ __forceinline__ void gload_lds16(const void* g, void* l) {
  __builtin_amdgcn_global_load_lds(
      (const __attribute__((address_space(1))) unsigned int*)g,
      (__attribute__((address_space(3))) unsigned int*)l, 16, 0, 0);
}

// ---- sync idiom: NO "memory" clobber anywhere (a mayLoad/mayStore asm forces
// SIInsertWaitcnts to drain vmcnt -> kills the in-flight pipeline, round-1 bug).
// Raw builtin s_barrier + clobberless s_waitcnt + sched_barrier(0) pins.
#define FENCE_() __builtin_amdgcn_sched_barrier(0)
// writer-side sync (gemm_rs/attn: plain LDS stores before, ds_reads after)
__device__ __forceinline__ void store_sync() {
  FENCE_();
  asm volatile("s_waitcnt lgkmcnt(0)");   // my ds_writes drained pre-barrier
  FENCE_();
  __builtin_amdgcn_s_barrier();
  FENCE_();                               // keep next ds_reads below barrier
}
// 8-phase leading gate: barrier first, then drain own ds_reads
__device__ __forceinline__ void phase_gate() {
  __builtin_amdgcn_s_barrier();
  asm volatile("s_waitcnt lgkmcnt(0)");
  FENCE_();
}
__device__ __forceinline__ void phase_close() {
  FENCE_();
  __builtin_amdgcn_s_barrier();
  FENCE_();
}

// ---------------- weight transpose + fp32->bf16 ----------------
__global__ void transpose_w(const float* __restrict__ in, unsigned short* __restrict__ out,
                            int R, int C) {
  __shared__ float tile[32][33];
  int c0 = blockIdx.x * 32, r0 = blockIdx.y * 32;
  int tx = threadIdx.x, ty = threadIdx.y;
#pragma unroll
  for (int i = 0; i < 32; i += 8)
    tile[ty + i][tx] = in[(size_t)(r0 + ty + i) * C + c0 + tx];
  __syncthreads();
#pragma unroll
  for (int i = 0; i < 32; i += 8)
    out[(size_t)(c0 + ty + i) * R + r0 + tx] = f2bfbits(tile[tx][ty + i]);
}

// ---------------- V transpose with per-64-token key permute ----------------
__global__ void transpose_v(const unsigned short* __restrict__ qkv,
                            unsigned short* __restrict__ vT, int M) {
  __shared__ unsigned short tile[32][33];
  int t0 = blockIdx.x * 32, c0 = blockIdx.y * 32;
  int tx = threadIdx.x, ty = threadIdx.y;
#pragma unroll
  for (int i = 0; i < 32; i += 8)
    tile[ty + i][tx] = qkv[(size_t)(t0 + ty + i) * N_QKV + 1536 + c0 + tx];
  __syncthreads();
  int t = t0 + tx;
  int c = t & 63;
  int kp = ((c >> 5) << 5) | (((c >> 2) & 3) << 3) | (((c >> 4) & 1) << 2) | (c & 3);
  size_t col = (size_t)(t & ~63) + kp;
#pragma unroll
  for (int i = 0; i < 32; i += 8)
    vT[(size_t)(c0 + ty + i) * M + col] = tile[tx][ty + i];
}

// ---------------- layernorm -> bf16 ----------------
__global__ void ln_bf16(const float* __restrict__ x, const float* __restrict__ g,
                        const float* __restrict__ be, unsigned short* __restrict__ out) {
  int row = blockIdx.x;
  const float* xr = x + (size_t)row * D_MODEL;
  int t = threadIdx.x;
  float v0 = xr[t], v1 = xr[t + 256], v2 = xr[t + 512];
  float s = v0 + v1 + v2;
  float s2 = v0 * v0 + v1 * v1 + v2 * v2;
#pragma unroll
  for (int off = 32; off > 0; off >>= 1) {
    s += __shfl_down(s, off, 64);
    s2 += __shfl_down(s2, off, 64);
  }
  __shared__ float red[8];
  int w = t >> 6, lane = t & 63;
  if (lane == 0) { red[w] = s; red[w + 4] = s2; }
  __syncthreads();
  if (t == 0) {
    float a = red[0] + red[1] + red[2] + red[3];
    float b = red[4] + red[5] + red[6] + red[7];
    red[0] = a * (1.0f / 768.0f);
    red[4] = b * (1.0f / 768.0f);
  }
  __syncthreads();
  float mu = red[0];
  float var = red[4] - mu * mu;
  float rs = rsqrtf(var + 1e-6f);
  unsigned short* orow = out + (size_t)row * D_MODEL;
  orow[t]       = f2bfbits((v0 - mu) * rs * g[t]       + be[t]);
  orow[t + 256] = f2bfbits((v1 - mu) * rs * g[t + 256] + be[t + 256]);
  orow[t + 512] = f2bfbits((v2 - mu) * rs * g[t + 512] + be[t + 512]);
}

// ---------------- bf16 MFMA GEMM 128x128 (Wo, FC2) --------------------------
// Round-2 change: clobberless sync -> the 2-deep uint4 register prefetch now
// stays in flight across barriers instead of being drained by forced vmcnt(0).
template <int EPI>
__global__ void __launch_bounds__(256, 3)
gemm_rs(const unsigned short* __restrict__ A,
        const unsigned short* __restrict__ Bt,
        const float* __restrict__ bias,
        const float* __restrict__ res,
        void* __restrict__ outv,
        int M, int N, int K) {
  __shared__ unsigned short lA[2][128 * 32];
  __shared__ unsigned short lB[2][128 * 32];
  int tid = threadIdx.x;
  int w = tid >> 6, lane = tid & 63;
  int id = blockIdx.x;
  int nn = N >> 7, bandM = (M >> 7) >> 3;
  int xcd = id & 7, s = id >> 3;
  int mt = xcd * bandM + s / nn;
  int nt = s - (s / nn) * nn;
  int m0 = mt * 128, n0 = nt * 128;
  int wm = (w >> 1) * 64, wn = (w & 1) * 64;
  f32x4 acc[4][4];
#pragma unroll
  for (int i = 0; i < 4; i++)
#pragma unroll
    for (int j = 0; j < 4; j++) acc[i][j] = (f32x4){0.f, 0.f, 0.f, 0.f};

  int sr = tid >> 2, sc = tid & 3;
  const unsigned short* gA = A + (size_t)(m0 + sr) * K + sc * 8;
  const unsigned short* gB = Bt + (size_t)(n0 + sr) * K + sc * 8;
  int wOff = sr * 64 + ((((sr >> 1) & 3) ^ sc) * 16);
  int fm = lane & 15, fg = lane >> 4;

  uint4 pA0, pA1, pB0, pB1;
  uint4 qA0, qA1, qB0, qB1;

  int nk = K >> 5;
  pA0 = *(const uint4*)(gA);
  pA1 = *(const uint4*)(gA + (size_t)64 * K);
  pB0 = *(const uint4*)(gB);
  pB1 = *(const uint4*)(gB + (size_t)64 * K);
  qA0 = *(const uint4*)(gA + 32);
  qA1 = *(const uint4*)(gA + (size_t)64 * K + 32);
  qB0 = *(const uint4*)(gB + 32);
  qB1 = *(const uint4*)(gB + (size_t)64 * K + 32);

  for (int k = 0; k < nk; k += 2) {
    {
      char* la = (char*)&lA[0][0];
      char* lb = (char*)&lB[0][0];
      *(uint4*)(la + wOff) = pA0;
      *(uint4*)(la + wOff + 4096) = pA1;
      *(uint4*)(lb + wOff) = pB0;
      *(uint4*)(lb + wOff + 4096) = pB1;
      if (k + 2 < nk) {
        int k0 = (k + 2) * 32;
        pA0 = *(const uint4*)(gA + k0);
        pA1 = *(const uint4*)(gA + (size_t)64 * K + k0);
        pB0 = *(const uint4*)(gB + k0);
        pB1 = *(const uint4*)(gB + (size_t)64 * K + k0);
      }
      store_sync();
      bf16x8 af[4], bfr[4];
#pragma unroll
      for (int i = 0; i < 4; i++) {
        int rr = wm + i * 16 + fm;
        af[i] = *(const bf16x8*)(la + rr * 64 + ((((rr >> 1) & 3) ^ fg) * 16));
      }
#pragma unroll
      for (int j = 0; j < 4; j++) {
        int rr = wn + j * 16 + fm;
        bfr[j] = *(const bf16x8*)(lb + rr * 64 + ((((rr >> 1) & 3) ^ fg) * 16));
      }
#pragma unroll
      for (int i = 0; i < 4; i++)
#pragma unroll
        for (int j = 0; j < 4; j++)
          acc[i][j] = __builtin_amdgcn_mfma_f32_16x16x32_bf16(af[i], bfr[j], acc[i][j], 0, 0, 0);
      store_sync();  // reads done before next iteration's LDS overwrite
    }
    {
      char* la = (char*)&lA[1][0];
      char* lb = (char*)&lB[1][0];
      *(uint4*)(la + wOff) = qA0;
      *(uint4*)(la + wOff + 4096) = qA1;
      *(uint4*)(lb + wOff) = qB0;
      *(uint4*)(lb + wOff + 4096) = qB1;
      if (k + 3 < nk) {
        int k0 = (k + 3) * 32;
        qA0 = *(const uint4*)(gA + k0);
        qA1 = *(const uint4*)(gA + (size_t)64 * K + k0);
        qB0 = *(const uint4*)(gB + k0);
        qB1 = *(const uint4*)(gB + (size_t)64 * K + k0);
      }
      store_sync();
      bf16x8 af[4], bfr[4];
#pragma unroll
      for (int i = 0; i < 4; i++) {
        int rr = wm + i * 16 + fm;
        af[i] = *(const bf16x8*)(la + rr * 64 + ((((rr >> 1) & 3) ^ fg) * 16));
      }
#pragma unroll
      for (int j = 0; j < 4; j++) {
        int rr = wn + j * 16 + fm;
        bfr[j] = *(const bf16x8*)(lb + rr * 64 + ((((rr >> 1) & 3) ^ fg) * 16));
      }
#pragma unroll
      for (int i = 0; i < 4; i++)
#pragma unroll
        for (int j = 0; j < 4; j++)
          acc[i][j] = __builtin_amdgcn_mfma_f32_16x16x32_bf16(af[i], bfr[j], acc[i][j], 0, 0, 0);
      store_sync();
    }
  }

  int er = (lane >> 4) * 4, ec = lane & 15;
#pragma unroll
  for (int i = 0; i < 4; i++) {
#pragma unroll
    for (int j = 0; j < 4; j++) {
      int n = n0 + wn + j * 16 + ec;
      float bv = bias[n];
#pragma unroll
      for (int r = 0; r < 4; r++) {
        int m = m0 + wm + i * 16 + er + r;
        float v = acc[i][j][r] + bv;
        if (EPI == 1) {
          v += res[(size_t)m * N + n];
          ((float*)outv)[(size_t)m * N + n] = v;
        } else {
          if (EPI == 2) v = 0.5f * v * (1.0f + erff(v * 0.70710678118f));
          ((unsigned short*)outv)[(size_t)m * N + n] = f2bfbits(v);
        }
      }
    }
  }
}

// ---------------- 256x256 8-phase GEMM (T2+T3+T4+T5, m201 template) ---------
// BM=BN=256, BK=64, 512 thr (8 waves, 2M x 4N), LDS 128 KiB. Staging via
// global_load_lds w/ pre-swizzled global source (linear LDS dest). Counted
// vmcnt(6) once per K-tile; never drained to 0 in the loop. Stage order per
// tile t: p1: A-ks1(t+1)  p2: B-ks0(t+2)  p3: B-ks1(t+2)  p4: A-ks0(t+2).
// WAR-safe at one-barrier separation: a slot's reads complete under the
// reader's lgkmcnt(0) before the trailing barrier; overwriting DMAs are
// issued only after that barrier.
template <int EPI>
__global__ void __launch_bounds__(512, 2)
gemm256(const unsigned short* __restrict__ A,
        const unsigned short* __restrict__ Bt,
        const float* __restrict__ bias,
        void* __restrict__ outv,
        int M, int N, int K) {
  __shared__ unsigned short sA[2][2][256 * 32];
  __shared__ unsigned short sB[2][2][256 * 32];
  const int tid = threadIdx.x;
  const int w = tid >> 6, lane = tid & 63;
  const int fm = lane & 15, fg = lane >> 4;

  const int id = blockIdx.x;
  const int nn = N >> 8, bandM = (M >> 8) >> 3;
  const int xcd = id & 7, sblk = id >> 3;
  const int mt = xcd * bandM + sblk / nn;
  const int nt = sblk - (sblk / nn) * nn;
  const int m0 = mt << 8, n0 = nt << 8;
  const int wm = (w >> 2) * 128, wn = (w & 3) * 64;

  f32x4 acc[8][4];
#pragma unroll
  for (int i = 0; i < 8; ++i)
#pragma unroll
    for (int j = 0; j < 4; ++j) acc[i][j] = (f32x4){0.f, 0.f, 0.f, 0.f};

  // loop-invariant ds_read byte offsets within one [256 x 32elem] ks-region
  int offA0[4], offA1[4], offB[4];
#pragma unroll
  for (int i = 0; i < 4; ++i) {
    int ra = wm + i * 16 + fm;
    offA0[i] = ra * 64 + ((((ra >> 1) & 3) ^ fg) * 16);
    int rb = wm + 64 + i * 16 + fm;
    offA1[i] = rb * 64 + ((((rb >> 1) & 3) ^ fg) * 16);
    int rc = wn + i * 16 + fm;
    offB[i] = rc * 64 + ((((rc >> 1) & 3) ^ fg) * 16);
  }

  // staging: lane l of wave w, call c -> linear LDS (w*2+c)*1024 + l*16
  const int r0 = w * 32 + (lane >> 2);
  const int cg = (lane & 3) ^ ((r0 >> 1) & 3);   // same for r0 and r0+16
  const unsigned short* gA0 = A + (size_t)(m0 + r0) * K + cg * 8;
  const unsigned short* gA1 = gA0 + (size_t)16 * K;
  const unsigned short* gB0 = Bt + (size_t)(n0 + r0) * K + cg * 8;
  const unsigned short* gB1 = gB0 + (size_t)16 * K;
  const int lo0 = w * 2048, lo1 = w * 2048 + 1024;
  const int NT = K >> 6;

  auto stA = [&](int kt, int ks, int buf) {
    int kk = kt < NT ? kt : NT - 1;     // clamp: uniform vmcnt accounting
    int off = kk * 64 + ks * 32;
    char* base = (char*)&sA[buf][ks][0];
    gload_lds16(gA0 + off, base + lo0);
    gload_lds16(gA1 + off, base + lo1);
  };
  auto stB = [&](int kt, int ks, int buf) {
    int kk = kt < NT ? kt : NT - 1;
    int off = kk * 64 + ks * 32;
    char* base = (char*)&sB[buf][ks][0];
    gload_lds16(gB0 + off, base + lo0);
    gload_lds16(gB1 + off, base + lo1);
  };

  // prologue: tile0 fully, then tile1 {B0,B1,A0}; 6 loads left in flight
  stB(0, 0, 0); stB(0, 1, 0); stA(0, 0, 0); stA(0, 1, 0);
  asm volatile("s_waitcnt vmcnt(4)");
  FENCE_();
  stB(1, 0, 1); stB(1, 1, 1); stA(1, 0, 1);
  asm volatile("s_waitcnt vmcnt(6)");
  FENCE_();
  __builtin_amdgcn_s_barrier();
  FENCE_();

  for (int t = 0; t < NT; ++t) {
    const int cur = t & 1;
    const char* As0 = (const char*)&sA[cur][0][0];
    const char* As1 = (const char*)&sA[cur][1][0];
    const char* Bs0 = (const char*)&sB[cur][0][0];
    const char* Bs1 = (const char*)&sB[cur][1][0];
    bf16x8 a[4], b0[4], b1[4];

    // ---- phase 1: (qm0, ks0); load B frags for both ks; stage A-ks1(t+1)
#pragma unroll
    for (int i = 0; i < 4; ++i) a[i] = *(const bf16x8*)(As0 + offA0[i]);
#pragma unroll
    for (int j = 0; j < 4; ++j) b0[j] = *(const bf16x8*)(Bs0 + offB[j]);
#pragma unroll
    for (int j = 0; j < 4; ++j) b1[j] = *(const bf16x8*)(Bs1 + offB[j]);
    stA(t + 1, 1, (t + 1) & 1);
    phase_gate();
    __builtin_amdgcn_s_setprio(1);
#pragma unroll
    for (int i = 0; i < 4; ++i)
#pragma unroll
      for (int j = 0; j < 4; ++j)
        acc[i][j] = __builtin_amdgcn_mfma_f32_16x16x32_bf16(a[i], b0[j], acc[i][j], 0, 0, 0);
    __builtin_amdgcn_s_setprio(0);
    phase_close();

    // ---- phase 2: (qm1, ks0); stage B-ks0(t+2)
#pragma unroll
    for (int i = 0; i < 4; ++i) a[i] = *(const bf16x8*)(As0 + offA1[i]);
    stB(t + 2, 0, cur);
    phase_gate();
    __builtin_amdgcn_s_setprio(1);
#pragma unroll
    for (int i = 0; i < 4; ++i)
#pragma unroll
      for (int j = 0; j < 4; ++j)
        acc[4 + i][j] = __builtin_amdgcn_mfma_f32_16x16x32_bf16(a[i], b0[j], acc[4 + i][j], 0, 0, 0);
    __builtin_amdgcn_s_setprio(0);
    phase_close();

    // ---- phase 3: (qm0, ks1); stage B-ks1(t+2)
#pragma unroll
    for (int i = 0; i < 4; ++i) a[i] = *(const bf16x8*)(As1 + offA0[i]);
    stB(t + 2, 1, cur);
    phase_gate();
    __builtin_amdgcn_s_setprio(1);
#pragma unroll
    for (int i = 0; i < 4; ++i)
#pragma unroll
      for (int j = 0; j < 4; ++j)
        acc[i][j] = __builtin_amdgcn_mfma_f32_16x16x32_bf16(a[i], b1[j], acc[i][j], 0, 0, 0);
    __builtin_amdgcn_s_setprio(0);
    phase_close();

    // ---- phase 4: (qm1, ks1); stage A-ks0(t+2); counted drain vmcnt(6)
#pragma unroll
    for (int i = 0; i < 4; ++i) a[i] = *(const bf16x8*)(As1 + offA1[i]);
    stA(t + 2, 0, cur);
    asm volatile("s_waitcnt vmcnt(6)");
    FENCE_();
    phase_gate();
    __builtin_amdgcn_s_setprio(1);
#pragma unroll
    for (int i = 0; i < 4; ++i)
#pragma unroll
      for (int j = 0; j < 4; ++j)
        acc[4 + i][j] = __builtin_amdgcn_mfma_f32_16x16x32_bf16(a[i], b1[j], acc[4 + i][j], 0, 0, 0);
    __builtin_amdgcn_s_setprio(0);
    phase_close();
  }

  // drain remaining async LDS-DMA before the workgroup can exit (LDS reuse
  // by the next block would otherwise race with late-landing DMA writes)
  asm volatile("s_waitcnt vmcnt(0)");
  FENCE_();

  const int er = fg * 4, ec = fm;
#pragma unroll
  for (int i = 0; i < 8; ++i) {
#pragma unroll
    for (int j = 0; j < 4; ++j) {
      int n = n0 + wn + j * 16 + ec;
      float bv = bias[n];
#pragma unroll
      for (int r = 0; r < 4; ++r) {
        int m = m0 + wm + i * 16 + er + r;
        float v = acc[i][j][r] + bv;
        if (EPI == 2) v = 0.5f * v * (1.0f + erff(v * 0.70710678118f));
        ((unsigned short*)outv)[(size_t)m * N + n] = f2bfbits(v);
      }
    }
  }
}

// ---------------- ragged flash attention v4 ---------------------------------
// Round-2: clobberless sync; K/V register prefetch survives the barrier.
__global__ void attn_flash4(const unsigned short* __restrict__ qkv,
                            const unsigned short* __restrict__ vT,
                            const int* __restrict__ cu,
                            unsigned short* __restrict__ out, int M) {
  int id = blockIdx.x;
  int qc = id / 96;
  int bh = id - qc * 96;
  int b = bh / 12, h = bh - b * 12;
  int tok0 = cu[b];
  int len = cu[b + 1] - tok0;
  if (qc * 128 >= len) return;

  __shared__ unsigned short lK[2][64 * 64];
  __shared__ unsigned short lVT[2][64 * 64];

  int tid = threadIdx.x, w = tid >> 6, lane = tid & 63;
  int fm = lane & 15, fg = lane >> 4;
  int xm = fm & 7;
  int qbase = qc * 128 + w * 32;

  bf16x8 qf[2][2];
#pragma unroll
  for (int qs = 0; qs < 2; qs++)
#pragma unroll
    for (int kh = 0; kh < 2; kh++)
      qf[qs][kh] = *(const bf16x8*)(qkv + (size_t)(tok0 + qbase + qs * 16 + fm) * N_QKV +
                                    h * 64 + kh * 32 + fg * 8);

  f32x4 Oacc[2][4];
#pragma unroll
  for (int qs = 0; qs < 2; qs++)
#pragma unroll
    for (int dt = 0; dt < 4; dt++) Oacc[qs][dt] = (f32x4){0.f, 0.f, 0.f, 0.f};
  float lrow[2] = {0.f, 0.f};
  const float C2 = 0.18033688011112042f;  // log2(e)/sqrt(64)

  int sr = tid >> 3, sp = tid & 7, sl = sp ^ (sr & 7);
  const unsigned short* kg0 = qkv + D_MODEL + h * 64 + sl * 8;
  const unsigned short* vg0 = vT + (size_t)(h * 64 + sr) * M + tok0 + sl * 8;

  uint4 rk0, rk1, rv0, rv1;
  auto gload = [&](int kt) {
    rk0 = *(const uint4*)(kg0 + (size_t)(tok0 + kt + sr) * N_QKV);
    rk1 = *(const uint4*)(kg0 + (size_t)(tok0 + kt + sr + 32) * N_QKV);
    rv0 = *(const uint4*)(vg0 + kt);
    rv1 = *(const uint4*)(vg0 + (size_t)32 * M + kt);
  };

  int nkt = len >> 6;
  gload(0);
  for (int kt = 0; kt < nkt; kt++) {
    int cur = kt & 1;
    *(uint4*)((char*)&lK[cur][0] + tid * 16) = rk0;
    *(uint4*)((char*)&lK[cur][0] + tid * 16 + 4096) = rk1;
    *(uint4*)((char*)&lVT[cur][0] + tid * 16) = rv0;
    *(uint4*)((char*)&lVT[cur][0] + tid * 16 + 4096) = rv1;
    if (kt + 1 < nkt) gload((kt + 1) * 64);
    store_sync();

    f32x4 s[2][4];
#pragma unroll
    for (int qs = 0; qs < 2; qs++)
#pragma unroll
      for (int t = 0; t < 4; t++) s[qs][t] = (f32x4){0.f, 0.f, 0.f, 0.f};
#pragma unroll
    for (int t = 0; t < 4; t++) {
      bf16x8 kf0 = *(const bf16x8*)&lK[cur][(t * 16 + fm) * 64 + ((fg ^ xm) * 8)];
      bf16x8 kf1 = *(const bf16x8*)&lK[cur][(t * 16 + fm) * 64 + (((4 + fg) ^ xm) * 8)];
#pragma unroll
      for (int qs = 0; qs < 2; qs++) {
        s[qs][t] = __builtin_amdgcn_mfma_f32_16x16x32_bf16(kf0, qf[qs][0], s[qs][t], 0, 0, 0);
        s[qs][t] = __builtin_amdgcn_mfma_f32_16x16x32_bf16(kf1, qf[qs][1], s[qs][t], 0, 0, 0);
      }
    }

    union { bf16x8 v; unsigned u[4]; } af[2][2];
#pragma unroll
    for (int qs = 0; qs < 2; qs++) {
      float ssum = 0.f;
#pragma unroll
      for (int t = 0; t < 4; t++) {
#pragma unroll
        for (int r = 0; r < 4; r++) {
          float p = exp2f(s[qs][t][r] * C2);
          s[qs][t][r] = p;
          ssum += p;
        }
      }
      lrow[qs] += ssum;
      af[qs][0].u[0] = pk2(s[qs][0][0], s[qs][0][1]);
      af[qs][0].u[1] = pk2(s[qs][0][2], s[qs][0][3]);
      af[qs][0].u[2] = pk2(s[qs][1][0], s[qs][1][1]);
      af[qs][0].u[3] = pk2(s[qs][1][2], s[qs][1][3]);
      af[qs][1].u[0] = pk2(s[qs][2][0], s[qs][2][1]);
      af[qs][1].u[1] = pk2(s[qs][2][2], s[qs][2][3]);
      af[qs][1].u[2] = pk2(s[qs][3][0], s[qs][3][1]);
      af[qs][1].u[3] = pk2(s[qs][3][2], s[qs][3][3]);
    }

#pragma unroll
    for (int dt = 0; dt < 4; dt++) {
      bf16x8 vf0 = *(const bf16x8*)&lVT[cur][(dt * 16 + fm) * 64 + ((fg ^ xm) * 8)];
      bf16x8 vf1 = *(const bf16x8*)&lVT[cur][(dt * 16 + fm) * 64 + (((4 + fg) ^ xm) * 8)];
#pragma unroll
      for (int qs = 0; qs < 2; qs++) {
        Oacc[qs][dt] = __builtin_amdgcn_mfma_f32_16x16x32_bf16(af[qs][0].v, vf0, Oacc[qs][dt], 0, 0, 0);
        Oacc[qs][dt] = __builtin_amdgcn_mfma_f32_16x16x32_bf16(af[qs][1].v, vf1, Oacc[qs][dt], 0, 0, 0);
      }
    }
    // reads of lK/lVT[cur] are complete (compiler lgkm waits precede MFMA
    // consumption); next iteration overwrites cur^1 only -> WAR-safe with
    // the single store_sync per iteration.
  }

#pragma unroll
  for (int qs = 0; qs < 2; qs++) {
    lrow[qs] += __shfl_xor(lrow[qs], 16, 64);
    lrow[qs] += __shfl_xor(lrow[qs], 32, 64);
    float inv = 1.0f / lrow[qs];
    float ir[4];
#pragma unroll
    for (int r = 0; r < 4; r++) ir[r] = __shfl(inv, fg * 4 + r, 64);
#pragma unroll
    for (int dt = 0; dt < 4; dt++)
#pragma unroll
      for (int r = 0; r < 4; r++)
        out[(size_t)(tok0 + qbase + qs * 16 + fg * 4 + r) * D_MODEL + h * 64 + dt * 16 + fm] =
            f2bfbits(Oacc[qs][dt][r] * ir[r]);
  }
}

extern "C" void kernel_launch(void* const* d_in, const int* in_sizes, int n_in,
                              void* d_out, int out_size, void* d_ws, size_t ws_size,
                              hipStream_t stream) {
  const float* x    = (const float*)d_in[0];
  const int* cu     = (const int*)d_in[1];
  const float* g1   = (const float*)d_in[2];
  const float* be1  = (const float*)d_in[3];
  const float* Wqkv = (const float*)d_in[4];
  const float* bqkv = (const float*)d_in[5];
  const float* Wo   = (const float*)d_in[6];
  const float* bo   = (const float*)d_in[7];
  const float* g2   = (const float*)d_in[8];
  const float* be2  = (const float*)d_in[9];
  const float* W1   = (const float*)d_in[10];
  const float* bfc1 = (const float*)d_in[11];
  const float* W2   = (const float*)d_in[12];
  const float* bfc2 = (const float*)d_in[13];
  float* out = (float*)d_out;
  int M = in_sizes[0] / D_MODEL;  // 6144

  unsigned short* WqkvT = (unsigned short*)d_ws;                       // 2304x768
  unsigned short* WoT   = WqkvT + 2304 * 768;                          // 768x768
  unsigned short* W1T   = WoT + 768 * 768;                             // 3072x768
  unsigned short* W2T   = W1T + 3072 * 768;                            // 768x3072
  unsigned short* bufA  = W2T + 768 * 3072;                            // M x 768 bf16
  float* x1             = (float*)(bufA + (size_t)M * D_MODEL);        // M x 768 f32
  unsigned short* qkvb  = (unsigned short*)(x1 + (size_t)M * D_MODEL); // M x 3072 bf16
  unsigned short* vT = (unsigned short*)x1;  // overlaps x1 (dead before Wo-gemm)

  dim3 b32(32, 8);
  transpose_w<<<dim3(2304 / 32, 768 / 32), b32, 0, stream>>>(Wqkv, WqkvT, 768, 2304);
  transpose_w<<<dim3(768 / 32, 768 / 32), b32, 0, stream>>>(Wo, WoT, 768, 768);
  transpose_w<<<dim3(3072 / 32, 768 / 32), b32, 0, stream>>>(W1, W1T, 768, 3072);
  transpose_w<<<dim3(768 / 32, 3072 / 32), b32, 0, stream>>>(W2, W2T, 3072, 768);

  ln_bf16<<<M, 256, 0, stream>>>(x, g1, be1, bufA);
  gemm256<0><<<(2304 / 256) * (M / 256), 512, 0, stream>>>(bufA, WqkvT, bqkv, qkvb, M, 2304, 768);
  transpose_v<<<dim3(M / 32, 768 / 32), b32, 0, stream>>>(qkvb, vT, M);
  attn_flash4<<<8 * 96, 256, 0, stream>>>(qkvb, vT, cu, bufA, M);
  gemm_rs<1><<<(768 / 128) * (M / 128), 256, 0, stream>>>(bufA, WoT, bo, x, x1, M, 768, 768);
  ln_bf16<<<M, 256, 0, stream>>>(x1, g2, be2, bufA);
  gemm256<2><<<(3072 / 256) * (M / 256), 512, 0, stream>>>(bufA, W1T, bfc1, qkvb, M, 3072, 768);
  gemm_rs<1><<<(768 / 128) * (M / 128), 256, 0, stream>>>(qkvb, W2T, bfc2, x1, out, M, 768, 3072);
}

// Round 3
// 361.493 us; speedup vs baseline: 1.1399x; 1.0538x over previous
//
#include <hip/hip_runtime.h>
#include <hip/hip_bf16.h>
#include <stdint.h>
#include <string.h>

#define D_MODEL 768
#define H_HEADS 12
#define HD_ 64
#define N_QKV 2304

typedef __bf16 bf16x8 __attribute__((ext_vector_type(8)));
typedef float f32x4 __attribute__((ext_vector_type(4)));
typedef __attribute__((address_space(3))) char lds_char;

__device__ __forceinline__ unsigned short f2bfbits(float f) {
  union { float f; unsigned u; } x; x.f = f;
  unsigned r = x.u + 0x7fffu + ((x.u >> 16) & 1u);
  return (unsigned short)(r >> 16);
}

// pack two non-negative floats to bf16 pair
__device__ __forceinline__ unsigned pk2(float a, float b) {
  union { float f; unsigned u; } x, y; x.f = a; y.f = b;
  return ((x.u + 0x8000u) >> 16) | ((y.u + 0x8000u) & 0xffff0000u);
}

// async global->LDS, 16B per lane; LDS dest = wave-uniform base + lane*16
__device__ __forceinline__ void gload_lds16(const void* g, void* l) {
  __builtin_amdgcn_global_load_lds(
      (const __attribute__((address_space(1))) unsigned int*)g,
      (__attribute__((address_space(3))) unsigned int*)l, 16, 0, 0);
}

// inline-asm ds_read_b128: invisible to SIInsertWaitcnts' LDS-DMA alias
// tracking -> no compiler-inserted vmcnt(0) drain before fragment reads
// (round-2 bottleneck). RAW vs DMA is owned by the explicit counted vmcnt;
// result-use ordering by lgkmcnt(0)+sched_barrier(0) (rule #18).
#define DSR(dst, ptr, IMM) \
  asm volatile("ds_read_b128 %0, %1 offset:%2" : "=v"(dst) : "v"(ptr), "n"(IMM))

#define FENCE_() __builtin_amdgcn_sched_barrier(0)
// writer-side sync (gemm_rs/attn: plain LDS stores before, ds_reads after)
__device__ __forceinline__ void store_sync() {
  FENCE_();
  asm volatile("s_waitcnt lgkmcnt(0)");
  FENCE_();
  __builtin_amdgcn_s_barrier();
  FENCE_();
}
// 8-phase leading gate: barrier first, then drain own ds_reads
__device__ __forceinline__ void phase_gate() {
  __builtin_amdgcn_s_barrier();
  asm volatile("s_waitcnt lgkmcnt(0)");
  FENCE_();
}
__device__ __forceinline__ void phase_close() {
  FENCE_();
  __builtin_amdgcn_s_barrier();
  FENCE_();
}

// ---------------- weight transpose + fp32->bf16 ----------------
__global__ void transpose_w(const float* __restrict__ in, unsigned short* __restrict__ out,
                            int R, int C) {
  __shared__ float tile[32][33];
  int c0 = blockIdx.x * 32, r0 = blockIdx.y * 32;
  int tx = threadIdx.x, ty = threadIdx.y;
#pragma unroll
  for (int i = 0; i < 32; i += 8)
    tile[ty + i][tx] = in[(size_t)(r0 + ty + i) * C + c0 + tx];
  __syncthreads();
#pragma unroll
  for (int i = 0; i < 32; i += 8)
    out[(size_t)(c0 + ty + i) * R + r0 + tx] = f2bfbits(tile[tx][ty + i]);
}

// ---------------- V transpose with per-64-token key permute ----------------
__global__ void transpose_v(const unsigned short* __restrict__ qkv,
                            unsigned short* __restrict__ vT, int M) {
  __shared__ unsigned short tile[32][33];
  int t0 = blockIdx.x * 32, c0 = blockIdx.y * 32;
  int tx = threadIdx.x, ty = threadIdx.y;
#pragma unroll
  for (int i = 0; i < 32; i += 8)
    tile[ty + i][tx] = qkv[(size_t)(t0 + ty + i) * N_QKV + 1536 + c0 + tx];
  __syncthreads();
  int t = t0 + tx;
  int c = t & 63;
  int kp = ((c >> 5) << 5) | (((c >> 2) & 3) << 3) | (((c >> 4) & 1) << 2) | (c & 3);
  size_t col = (size_t)(t & ~63) + kp;
#pragma unroll
  for (int i = 0; i < 32; i += 8)
    vT[(size_t)(c0 + ty + i) * M + col] = tile[tx][ty + i];
}

// ---------------- layernorm -> bf16 ----------------
__global__ void ln_bf16(const float* __restrict__ x, const float* __restrict__ g,
                        const float* __restrict__ be, unsigned short* __restrict__ out) {
  int row = blockIdx.x;
  const float* xr = x + (size_t)row * D_MODEL;
  int t = threadIdx.x;
  float v0 = xr[t], v1 = xr[t + 256], v2 = xr[t + 512];
  float s = v0 + v1 + v2;
  float s2 = v0 * v0 + v1 * v1 + v2 * v2;
#pragma unroll
  for (int off = 32; off > 0; off >>= 1) {
    s += __shfl_down(s, off, 64);
    s2 += __shfl_down(s2, off, 64);
  }
  __shared__ float red[8];
  int w = t >> 6, lane = t & 63;
  if (lane == 0) { red[w] = s; red[w + 4] = s2; }
  __syncthreads();
  if (t == 0) {
    float a = red[0] + red[1] + red[2] + red[3];
    float b = red[4] + red[5] + red[6] + red[7];
    red[0] = a * (1.0f / 768.0f);
    red[4] = b * (1.0f / 768.0f);
  }
  __syncthreads();
  float mu = red[0];
  float var = red[4] - mu * mu;
  float rs = rsqrtf(var + 1e-6f);
  unsigned short* orow = out + (size_t)row * D_MODEL;
  orow[t]       = f2bfbits((v0 - mu) * rs * g[t]       + be[t]);
  orow[t + 256] = f2bfbits((v1 - mu) * rs * g[t + 256] + be[t + 256]);
  orow[t + 512] = f2bfbits((v2 - mu) * rs * g[t + 512] + be[t + 512]);
}

// ---------------- bf16 MFMA GEMM 128x128 (Wo, FC2) --------------------------
template <int EPI>
__global__ void __launch_bounds__(256, 3)
gemm_rs(const unsigned short* __restrict__ A,
        const unsigned short* __restrict__ Bt,
        const float* __restrict__ bias,
        const float* __restrict__ res,
        void* __restrict__ outv,
        int M, int N, int K) {
  __shared__ unsigned short lA[2][128 * 32];
  __shared__ unsigned short lB[2][128 * 32];
  int tid = threadIdx.x;
  int w = tid >> 6, lane = tid & 63;
  int id = blockIdx.x;
  int nn = N >> 7, bandM = (M >> 7) >> 3;
  int xcd = id & 7, s = id >> 3;
  int mt = xcd * bandM + s / nn;
  int nt = s - (s / nn) * nn;
  int m0 = mt * 128, n0 = nt * 128;
  int wm = (w >> 1) * 64, wn = (w & 1) * 64;
  f32x4 acc[4][4];
#pragma unroll
  for (int i = 0; i < 4; i++)
#pragma unroll
    for (int j = 0; j < 4; j++) acc[i][j] = (f32x4){0.f, 0.f, 0.f, 0.f};

  int sr = tid >> 2, sc = tid & 3;
  const unsigned short* gA = A + (size_t)(m0 + sr) * K + sc * 8;
  const unsigned short* gB = Bt + (size_t)(n0 + sr) * K + sc * 8;
  int wOff = sr * 64 + ((((sr >> 1) & 3) ^ sc) * 16);
  int fm = lane & 15, fg = lane >> 4;

  uint4 pA0, pA1, pB0, pB1;
  uint4 qA0, qA1, qB0, qB1;

  int nk = K >> 5;
  pA0 = *(const uint4*)(gA);
  pA1 = *(const uint4*)(gA + (size_t)64 * K);
  pB0 = *(const uint4*)(gB);
  pB1 = *(const uint4*)(gB + (size_t)64 * K);
  qA0 = *(const uint4*)(gA + 32);
  qA1 = *(const uint4*)(gA + (size_t)64 * K + 32);
  qB0 = *(const uint4*)(gB + 32);
  qB1 = *(const uint4*)(gB + (size_t)64 * K + 32);

  for (int k = 0; k < nk; k += 2) {
    {
      char* la = (char*)&lA[0][0];
      char* lb = (char*)&lB[0][0];
      *(uint4*)(la + wOff) = pA0;
      *(uint4*)(la + wOff + 4096) = pA1;
      *(uint4*)(lb + wOff) = pB0;
      *(uint4*)(lb + wOff + 4096) = pB1;
      if (k + 2 < nk) {
        int k0 = (k + 2) * 32;
        pA0 = *(const uint4*)(gA + k0);
        pA1 = *(const uint4*)(gA + (size_t)64 * K + k0);
        pB0 = *(const uint4*)(gB + k0);
        pB1 = *(const uint4*)(gB + (size_t)64 * K + k0);
      }
      store_sync();
      bf16x8 af[4], bfr[4];
#pragma unroll
      for (int i = 0; i < 4; i++) {
        int rr = wm + i * 16 + fm;
        af[i] = *(const bf16x8*)(la + rr * 64 + ((((rr >> 1) & 3) ^ fg) * 16));
      }
#pragma unroll
      for (int j = 0; j < 4; j++) {
        int rr = wn + j * 16 + fm;
        bfr[j] = *(const bf16x8*)(lb + rr * 64 + ((((rr >> 1) & 3) ^ fg) * 16));
      }
#pragma unroll
      for (int i = 0; i < 4; i++)
#pragma unroll
        for (int j = 0; j < 4; j++)
          acc[i][j] = __builtin_amdgcn_mfma_f32_16x16x32_bf16(af[i], bfr[j], acc[i][j], 0, 0, 0);
      store_sync();
    }
    {
      char* la = (char*)&lA[1][0];
      char* lb = (char*)&lB[1][0];
      *(uint4*)(la + wOff) = qA0;
      *(uint4*)(la + wOff + 4096) = qA1;
      *(uint4*)(lb + wOff) = qB0;
      *(uint4*)(lb + wOff + 4096) = qB1;
      if (k + 3 < nk) {
        int k0 = (k + 3) * 32;
        qA0 = *(const uint4*)(gA + k0);
        qA1 = *(const uint4*)(gA + (size_t)64 * K + k0);
        qB0 = *(const uint4*)(gB + k0);
        qB1 = *(const uint4*)(gB + (size_t)64 * K + k0);
      }
      store_sync();
      bf16x8 af[4], bfr[4];
#pragma unroll
      for (int i = 0; i < 4; i++) {
        int rr = wm + i * 16 + fm;
        af[i] = *(const bf16x8*)(la + rr * 64 + ((((rr >> 1) & 3) ^ fg) * 16));
      }
#pragma unroll
      for (int j = 0; j < 4; j++) {
        int rr = wn + j * 16 + fm;
        bfr[j] = *(const bf16x8*)(lb + rr * 64 + ((((rr >> 1) & 3) ^ fg) * 16));
      }
#pragma unroll
      for (int i = 0; i < 4; i++)
#pragma unroll
        for (int j = 0; j < 4; j++)
          acc[i][j] = __builtin_amdgcn_mfma_f32_16x16x32_bf16(af[i], bfr[j], acc[i][j], 0, 0, 0);
      store_sync();
    }
  }

  int er = (lane >> 4) * 4, ec = lane & 15;
#pragma unroll
  for (int i = 0; i < 4; i++) {
#pragma unroll
    for (int j = 0; j < 4; j++) {
      int n = n0 + wn + j * 16 + ec;
      float bv = bias[n];
#pragma unroll
      for (int r = 0; r < 4; r++) {
        int m = m0 + wm + i * 16 + er + r;
        float v = acc[i][j][r] + bv;
        if (EPI == 1) {
          v += res[(size_t)m * N + n];
          ((float*)outv)[(size_t)m * N + n] = v;
        } else {
          if (EPI == 2) v = 0.5f * v * (1.0f + erff(v * 0.70710678118f));
          ((unsigned short*)outv)[(size_t)m * N + n] = f2bfbits(v);
        }
      }
    }
  }
}

// ---------------- 256x256 8-phase GEMM (T2+T3+T4+T5, m201 template) ---------
// Round-3: fragment reads via inline-asm ds_read_b128 with offset: immediates
// (base VGPR per A/B region; rows +1024B, qm +4096, ks +16384, dbuf +32768 --
// XOR-swizzle term invariant across all these strides). No compiler-visible
// ds op remains in the loop, so no LDS-DMA alias vmcnt drains.
template <int EPI>
__global__ void __launch_bounds__(512, 2)
gemm256(const unsigned short* __restrict__ A,
        const unsigned short* __restrict__ Bt,
        const float* __restrict__ bias,
        void* __restrict__ outv,
        int M, int N, int K) {
  __shared__ unsigned short sA[2][2][256 * 32];
  __shared__ unsigned short sB[2][2][256 * 32];
  const int tid = threadIdx.x;
  const int w = tid >> 6, lane = tid & 63;
  const int fm = lane & 15, fg = lane >> 4;

  const int id = blockIdx.x;
  const int nn = N >> 8, bandM = (M >> 8) >> 3;
  const int xcd = id & 7, sblk = id >> 3;
  const int mt = xcd * bandM + sblk / nn;
  const int nt = sblk - (sblk / nn) * nn;
  const int m0 = mt << 8, n0 = nt << 8;
  const int wm = (w >> 2) * 128, wn = (w & 3) * 64;

  f32x4 acc[8][4];
#pragma unroll
  for (int i = 0; i < 8; ++i)
#pragma unroll
    for (int j = 0; j < 4; ++j) acc[i][j] = (f32x4){0.f, 0.f, 0.f, 0.f};

  // per-wave/lane fragment base byte offsets (swizzle term const across rows)
  const unsigned aoff0 = (unsigned)((wm + fm) * 64 + ((((wm + fm) >> 1) & 3) ^ fg) * 16);
  const unsigned boff0 = (unsigned)((wn + fm) * 64 + ((((wn + fm) >> 1) & 3) ^ fg) * 16);
  const char* sAb = (const char*)&sA[0][0][0];
  const char* sBb = (const char*)&sB[0][0][0];

  // staging: lane l of wave w, call c -> linear LDS (w*2+c)*1024 + l*16
  const int r0 = w * 32 + (lane >> 2);
  const int cg = (lane & 3) ^ ((r0 >> 1) & 3);   // same for r0 and r0+16
  const unsigned short* gA0 = A + (size_t)(m0 + r0) * K + cg * 8;
  const unsigned short* gA1 = gA0 + (size_t)16 * K;
  const unsigned short* gB0 = Bt + (size_t)(n0 + r0) * K + cg * 8;
  const unsigned short* gB1 = gB0 + (size_t)16 * K;
  const int lo0 = w * 2048, lo1 = w * 2048 + 1024;
  const int NT = K >> 6;

  auto stA = [&](int kt, int ks, int buf) {
    int kk = kt < NT ? kt : NT - 1;     // clamp: uniform vmcnt accounting
    int off = kk * 64 + ks * 32;
    char* base = (char*)&sA[buf][ks][0];
    gload_lds16(gA0 + off, base + lo0);
    gload_lds16(gA1 + off, base + lo1);
  };
  auto stB = [&](int kt, int ks, int buf) {
    int kk = kt < NT ? kt : NT - 1;
    int off = kk * 64 + ks * 32;
    char* base = (char*)&sB[buf][ks][0];
    gload_lds16(gB0 + off, base + lo0);
    gload_lds16(gB1 + off, base + lo1);
  };

  // prologue: tile0 fully, then tile1 {B0,B1,A0}; 6 loads left in flight
  stB(0, 0, 0); stB(0, 1, 0); stA(0, 0, 0); stA(0, 1, 0);
  asm volatile("s_waitcnt vmcnt(4)");
  FENCE_();
  stB(1, 0, 1); stB(1, 1, 1); stA(1, 0, 1);
  asm volatile("s_waitcnt vmcnt(6)");
  FENCE_();
  __builtin_amdgcn_s_barrier();
  FENCE_();

  for (int t = 0; t < NT; ++t) {
    const int cur = t & 1;
    const lds_char* pa = (const lds_char*)(sAb + cur * 32768 + aoff0);
    const lds_char* pb = (const lds_char*)(sBb + cur * 32768 + boff0);
    bf16x8 a[4], b0[4], b1[4];

    // ---- phase 1: (qm0, ks0); B frags for both ks; stage A-ks1(t+1)
    DSR(a[0], pa, 0);     DSR(a[1], pa, 1024);  DSR(a[2], pa, 2048);  DSR(a[3], pa, 3072);
    DSR(b0[0], pb, 0);    DSR(b0[1], pb, 1024); DSR(b0[2], pb, 2048); DSR(b0[3], pb, 3072);
    DSR(b1[0], pb, 16384);DSR(b1[1], pb, 17408);DSR(b1[2], pb, 18432);DSR(b1[3], pb, 19456);
    stA(t + 1, 1, (t + 1) & 1);
    phase_gate();
    __builtin_amdgcn_s_setprio(1);
#pragma unroll
    for (int i = 0; i < 4; ++i)
#pragma unroll
      for (int j = 0; j < 4; ++j)
        acc[i][j] = __builtin_amdgcn_mfma_f32_16x16x32_bf16(a[i], b0[j], acc[i][j], 0, 0, 0);
    __builtin_amdgcn_s_setprio(0);
    phase_close();

    // ---- phase 2: (qm1, ks0); stage B-ks0(t+2)
    DSR(a[0], pa, 4096);  DSR(a[1], pa, 5120);  DSR(a[2], pa, 6144);  DSR(a[3], pa, 7168);
    stB(t + 2, 0, cur);
    phase_gate();
    __builtin_amdgcn_s_setprio(1);
#pragma unroll
    for (int i = 0; i < 4; ++i)
#pragma unroll
      for (int j = 0; j < 4; ++j)
        acc[4 + i][j] = __builtin_amdgcn_mfma_f32_16x16x32_bf16(a[i], b0[j], acc[4 + i][j], 0, 0, 0);
    __builtin_amdgcn_s_setprio(0);
    phase_close();

    // ---- phase 3: (qm0, ks1); stage B-ks1(t+2)
    DSR(a[0], pa, 16384); DSR(a[1], pa, 17408); DSR(a[2], pa, 18432); DSR(a[3], pa, 19456);
    stB(t + 2, 1, cur);
    phase_gate();
    __builtin_amdgcn_s_setprio(1);
#pragma unroll
    for (int i = 0; i < 4; ++i)
#pragma unroll
      for (int j = 0; j < 4; ++j)
        acc[i][j] = __builtin_amdgcn_mfma_f32_16x16x32_bf16(a[i], b1[j], acc[i][j], 0, 0, 0);
    __builtin_amdgcn_s_setprio(0);
    phase_close();

    // ---- phase 4: (qm1, ks1); stage A-ks0(t+2); counted drain vmcnt(6)
    DSR(a[0], pa, 20480); DSR(a[1], pa, 21504); DSR(a[2], pa, 22528); DSR(a[3], pa, 23552);
    stA(t + 2, 0, cur);
    asm volatile("s_waitcnt vmcnt(6)");
    FENCE_();
    phase_gate();
    __builtin_amdgcn_s_setprio(1);
#pragma unroll
    for (int i = 0; i < 4; ++i)
#pragma unroll
      for (int j = 0; j < 4; ++j)
        acc[4 + i][j] = __builtin_amdgcn_mfma_f32_16x16x32_bf16(a[i], b1[j], acc[4 + i][j], 0, 0, 0);
    __builtin_amdgcn_s_setprio(0);
    phase_close();
  }

  // drain remaining async LDS-DMA before the workgroup can exit
  asm volatile("s_waitcnt vmcnt(0)");
  FENCE_();

  const int er = fg * 4, ec = fm;
#pragma unroll
  for (int i = 0; i < 8; ++i) {
#pragma unroll
    for (int j = 0; j < 4; ++j) {
      int n = n0 + wn + j * 16 + ec;
      float bv = bias[n];
#pragma unroll
      for (int r = 0; r < 4; ++r) {
        int m = m0 + wm + i * 16 + er + r;
        float v = acc[i][j][r] + bv;
        if (EPI == 2) v = 0.5f * v * (1.0f + erff(v * 0.70710678118f));
        ((unsigned short*)outv)[(size_t)m * N + n] = f2bfbits(v);
      }
    }
  }
}

// ---------------- ragged flash attention v4 ---------------------------------
__global__ void attn_flash4(const unsigned short* __restrict__ qkv,
                            const unsigned short* __restrict__ vT,
                            const int* __restrict__ cu,
                            unsigned short* __restrict__ out, int M) {
  int id = blockIdx.x;
  int qc = id / 96;
  int bh = id - qc * 96;
  int b = bh / 12, h = bh - b * 12;
  int tok0 = cu[b];
  int len = cu[b + 1] - tok0;
  if (qc * 128 >= len) return;

  __shared__ unsigned short lK[2][64 * 64];
  __shared__ unsigned short lVT[2][64 * 64];

  int tid = threadIdx.x, w = tid >> 6, lane = tid & 63;
  int fm = lane & 15, fg = lane >> 4;
  int xm = fm & 7;
  int qbase = qc * 128 + w * 32;

  bf16x8 qf[2][2];
#pragma unroll
  for (int qs = 0; qs < 2; qs++)
#pragma unroll
    for (int kh = 0; kh < 2; kh++)
      qf[qs][kh] = *(const bf16x8*)(qkv + (size_t)(tok0 + qbase + qs * 16 + fm) * N_QKV +
                                    h * 64 + kh * 32 + fg * 8);

  f32x4 Oacc[2][4];
#pragma unroll
  for (int qs = 0; qs < 2; qs++)
#pragma unroll
    for (int dt = 0; dt < 4; dt++) Oacc[qs][dt] = (f32x4){0.f, 0.f, 0.f, 0.f};
  float lrow[2] = {0.f, 0.f};
  const float C2 = 0.18033688011112042f;  // log2(e)/sqrt(64)

  int sr = tid >> 3, sp = tid & 7, sl = sp ^ (sr & 7);
  const unsigned short* kg0 = qkv + D_MODEL + h * 64 + sl * 8;
  const unsigned short* vg0 = vT + (size_t)(h * 64 + sr) * M + tok0 + sl * 8;

  uint4 rk0, rk1, rv0, rv1;
  auto gload = [&](int kt) {
    rk0 = *(const uint4*)(kg0 + (size_t)(tok0 + kt + sr) * N_QKV);
    rk1 = *(const uint4*)(kg0 + (size_t)(tok0 + kt + sr + 32) * N_QKV);
    rv0 = *(const uint4*)(vg0 + kt);
    rv1 = *(const uint4*)(vg0 + (size_t)32 * M + kt);
  };

  int nkt = len >> 6;
  gload(0);
  for (int kt = 0; kt < nkt; kt++) {
    int cur = kt & 1;
    *(uint4*)((char*)&lK[cur][0] + tid * 16) = rk0;
    *(uint4*)((char*)&lK[cur][0] + tid * 16 + 4096) = rk1;
    *(uint4*)((char*)&lVT[cur][0] + tid * 16) = rv0;
    *(uint4*)((char*)&lVT[cur][0] + tid * 16 + 4096) = rv1;
    if (kt + 1 < nkt) gload((kt + 1) * 64);
    store_sync();

    f32x4 s[2][4];
#pragma unroll
    for (int qs = 0; qs < 2; qs++)
#pragma unroll
      for (int t = 0; t < 4; t++) s[qs][t] = (f32x4){0.f, 0.f, 0.f, 0.f};
#pragma unroll
    for (int t = 0; t < 4; t++) {
      bf16x8 kf0 = *(const bf16x8*)&lK[cur][(t * 16 + fm) * 64 + ((fg ^ xm) * 8)];
      bf16x8 kf1 = *(const bf16x8*)&lK[cur][(t * 16 + fm) * 64 + (((4 + fg) ^ xm) * 8)];
#pragma unroll
      for (int qs = 0; qs < 2; qs++) {
        s[qs][t] = __builtin_amdgcn_mfma_f32_16x16x32_bf16(kf0, qf[qs][0], s[qs][t], 0, 0, 0);
        s[qs][t] = __builtin_amdgcn_mfma_f32_16x16x32_bf16(kf1, qf[qs][1], s[qs][t], 0, 0, 0);
      }
    }

    union { bf16x8 v; unsigned u[4]; } af[2][2];
#pragma unroll
    for (int qs = 0; qs < 2; qs++) {
      float ssum = 0.f;
#pragma unroll
      for (int t = 0; t < 4; t++) {
#pragma unroll
        for (int r = 0; r < 4; r++) {
          float p = exp2f(s[qs][t][r] * C2);
          s[qs][t][r] = p;
          ssum += p;
        }
      }
      lrow[qs] += ssum;
      af[qs][0].u[0] = pk2(s[qs][0][0], s[qs][0][1]);
      af[qs][0].u[1] = pk2(s[qs][0][2], s[qs][0][3]);
      af[qs][0].u[2] = pk2(s[qs][1][0], s[qs][1][1]);
      af[qs][0].u[3] = pk2(s[qs][1][2], s[qs][1][3]);
      af[qs][1].u[0] = pk2(s[qs][2][0], s[qs][2][1]);
      af[qs][1].u[1] = pk2(s[qs][2][2], s[qs][2][3]);
      af[qs][1].u[2] = pk2(s[qs][3][0], s[qs][3][1]);
      af[qs][1].u[3] = pk2(s[qs][3][2], s[qs][3][3]);
    }

#pragma unroll
    for (int dt = 0; dt < 4; dt++) {
      bf16x8 vf0 = *(const bf16x8*)&lVT[cur][(dt * 16 + fm) * 64 + ((fg ^ xm) * 8)];
      bf16x8 vf1 = *(const bf16x8*)&lVT[cur][(dt * 16 + fm) * 64 + (((4 + fg) ^ xm) * 8)];
#pragma unroll
      for (int qs = 0; qs < 2; qs++) {
        Oacc[qs][dt] = __builtin_amdgcn_mfma_f32_16x16x32_bf16(af[qs][0].v, vf0, Oacc[qs][dt], 0, 0, 0);
        Oacc[qs][dt] = __builtin_amdgcn_mfma_f32_16x16x32_bf16(af[qs][1].v, vf1, Oacc[qs][dt], 0, 0, 0);
      }
    }
  }

#pragma unroll
  for (int qs = 0; qs < 2; qs++) {
    lrow[qs] += __shfl_xor(lrow[qs], 16, 64);
    lrow[qs] += __shfl_xor(lrow[qs], 32, 64);
    float inv = 1.0f / lrow[qs];
    float ir[4];
#pragma unroll
    for (int r = 0; r < 4; r++) ir[r] = __shfl(inv, fg * 4 + r, 64);
#pragma unroll
    for (int dt = 0; dt < 4; dt++)
#pragma unroll
      for (int r = 0; r < 4; r++)
        out[(size_t)(tok0 + qbase + qs * 16 + fg * 4 + r) * D_MODEL + h * 64 + dt * 16 + fm] =
            f2bfbits(Oacc[qs][dt][r] * ir[r]);
  }
}

extern "C" void kernel_launch(void* const* d_in, const int* in_sizes, int n_in,
                              void* d_out, int out_size, void* d_ws, size_t ws_size,
                              hipStream_t stream) {
  const float* x    = (const float*)d_in[0];
  const int* cu     = (const int*)d_in[1];
  const float* g1   = (const float*)d_in[2];
  const float* be1  = (const float*)d_in[3];
  const float* Wqkv = (const float*)d_in[4];
  const float* bqkv = (const float*)d_in[5];
  const float* Wo   = (const float*)d_in[6];
  const float* bo   = (const float*)d_in[7];
  const float* g2   = (const float*)d_in[8];
  const float* be2  = (const float*)d_in[9];
  const float* W1   = (const float*)d_in[10];
  const float* bfc1 = (const float*)d_in[11];
  const float* W2   = (const float*)d_in[12];
  const float* bfc2 = (const float*)d_in[13];
  float* out = (float*)d_out;
  int M = in_sizes[0] / D_MODEL;  // 6144

  unsigned short* WqkvT = (unsigned short*)d_ws;                       // 2304x768
  unsigned short* WoT   = WqkvT + 2304 * 768;                          // 768x768
  unsigned short* W1T   = WoT + 768 * 768;                             // 3072x768
  unsigned short* W2T   = W1T + 3072 * 768;                            // 768x3072
  unsigned short* bufA  = W2T + 768 * 3072;                            // M x 768 bf16
  float* x1             = (float*)(bufA + (size_t)M * D_MODEL);        // M x 768 f32
  unsigned short* qkvb  = (unsigned short*)(x1 + (size_t)M * D_MODEL); // M x 3072 bf16
  unsigned short* vT = (unsigned short*)x1;  // overlaps x1 (dead before Wo-gemm)

  dim3 b32(32, 8);
  transpose_w<<<dim3(2304 / 32, 768 / 32), b32, 0, stream>>>(Wqkv, WqkvT, 768, 2304);
  transpose_w<<<dim3(768 / 32, 768 / 32), b32, 0, stream>>>(Wo, WoT, 768, 768);
  transpose_w<<<dim3(3072 / 32, 768 / 32), b32, 0, stream>>>(W1, W1T, 768, 3072);
  transpose_w<<<dim3(768 / 32, 3072 / 32), b32, 0, stream>>>(W2, W2T, 3072, 768);

  ln_bf16<<<M, 256, 0, stream>>>(x, g1, be1, bufA);
  gemm256<0><<<(2304 / 256) * (M / 256), 512, 0, stream>>>(bufA, WqkvT, bqkv, qkvb, M, 2304, 768);
  transpose_v<<<dim3(M / 32, 768 / 32), b32, 0, stream>>>(qkvb, vT, M);
  attn_flash4<<<8 * 96, 256, 0, stream>>>(qkvb, vT, cu, bufA, M);
  gemm_rs<1><<<(768 / 128) * (M / 128), 256, 0, stream>>>(bufA, WoT, bo, x, x1, M, 768, 768);
  ln_bf16<<<M, 256, 0, stream>>>(x1, g2, be2, bufA);
  gemm256<2><<<(3072 / 256) * (M / 256), 512, 0, stream>>>(bufA, W1T, bfc1, qkvb, M, 3072, 768);
  gemm_rs<1><<<(768 / 128) * (M / 128), 256, 0, stream>>>(qkvb, W2T, bfc2, x1, out, M, 768, 3072);
}

// Round 4
// 344.663 us; speedup vs baseline: 1.1956x; 1.0488x over previous
//
#include <hip/hip_runtime.h>
#include <hip/hip_bf16.h>
#include <stdint.h>
#include <string.h>

#define D_MODEL 768
#define H_HEADS 12
#define HD_ 64
#define N_QKV 2304

typedef __bf16 bf16x8 __attribute__((ext_vector_type(8)));
typedef float f32x4 __attribute__((ext_vector_type(4)));

__device__ __forceinline__ unsigned short f2bfbits(float f) {
  union { float f; unsigned u; } x; x.f = f;
  unsigned r = x.u + 0x7fffu + ((x.u >> 16) & 1u);
  return (unsigned short)(r >> 16);
}

// pack two non-negative floats to bf16 pair
__device__ __forceinline__ unsigned pk2(float a, float b) {
  union { float f; unsigned u; } x, y; x.f = a; y.f = b;
  return ((x.u + 0x8000u) >> 16) | ((y.u + 0x8000u) & 0xffff0000u);
}

// ---- sync idiom: NO "memory" clobber (a mayLoad/mayStore asm forces
// SIInsertWaitcnts to drain vmcnt -> kills in-flight global prefetch;
// proven by the round-1->2 gemm256 delta 147->93us). Raw s_barrier +
// clobberless s_waitcnt + sched_barrier(0) ordering pins.
#define FENCE_() __builtin_amdgcn_sched_barrier(0)
__device__ __forceinline__ void store_sync() {
  FENCE_();
  asm volatile("s_waitcnt lgkmcnt(0)");   // own ds_writes drained pre-barrier
  FENCE_();
  __builtin_amdgcn_s_barrier();
  FENCE_();                               // keep following ds ops below barrier
}

// ---------------- weight transpose + fp32->bf16 ----------------
__global__ void transpose_w(const float* __restrict__ in, unsigned short* __restrict__ out,
                            int R, int C) {
  __shared__ float tile[32][33];
  int c0 = blockIdx.x * 32, r0 = blockIdx.y * 32;
  int tx = threadIdx.x, ty = threadIdx.y;
#pragma unroll
  for (int i = 0; i < 32; i += 8)
    tile[ty + i][tx] = in[(size_t)(r0 + ty + i) * C + c0 + tx];
  __syncthreads();
#pragma unroll
  for (int i = 0; i < 32; i += 8)
    out[(size_t)(c0 + ty + i) * R + r0 + tx] = f2bfbits(tile[tx][ty + i]);
}

// ---------------- V transpose with per-64-token key permute ----------------
__global__ void transpose_v(const unsigned short* __restrict__ qkv,
                            unsigned short* __restrict__ vT, int M) {
  __shared__ unsigned short tile[32][33];
  int t0 = blockIdx.x * 32, c0 = blockIdx.y * 32;
  int tx = threadIdx.x, ty = threadIdx.y;
#pragma unroll
  for (int i = 0; i < 32; i += 8)
    tile[ty + i][tx] = qkv[(size_t)(t0 + ty + i) * N_QKV + 1536 + c0 + tx];
  __syncthreads();
  int t = t0 + tx;
  int c = t & 63;
  int kp = ((c >> 5) << 5) | (((c >> 2) & 3) << 3) | (((c >> 4) & 1) << 2) | (c & 3);
  size_t col = (size_t)(t & ~63) + kp;
#pragma unroll
  for (int i = 0; i < 32; i += 8)
    vT[(size_t)(c0 + ty + i) * M + col] = tile[tx][ty + i];
}

// ---------------- layernorm -> bf16 ----------------
__global__ void ln_bf16(const float* __restrict__ x, const float* __restrict__ g,
                        const float* __restrict__ be, unsigned short* __restrict__ out) {
  int row = blockIdx.x;
  const float* xr = x + (size_t)row * D_MODEL;
  int t = threadIdx.x;
  float v0 = xr[t], v1 = xr[t + 256], v2 = xr[t + 512];
  float s = v0 + v1 + v2;
  float s2 = v0 * v0 + v1 * v1 + v2 * v2;
#pragma unroll
  for (int off = 32; off > 0; off >>= 1) {
    s += __shfl_down(s, off, 64);
    s2 += __shfl_down(s2, off, 64);
  }
  __shared__ float red[8];
  int w = t >> 6, lane = t & 63;
  if (lane == 0) { red[w] = s; red[w + 4] = s2; }
  __syncthreads();
  if (t == 0) {
    float a = red[0] + red[1] + red[2] + red[3];
    float b = red[4] + red[5] + red[6] + red[7];
    red[0] = a * (1.0f / 768.0f);
    red[4] = b * (1.0f / 768.0f);
  }
  __syncthreads();
  float mu = red[0];
  float var = red[4] - mu * mu;
  float rs = rsqrtf(var + 1e-6f);
  unsigned short* orow = out + (size_t)row * D_MODEL;
  orow[t]       = f2bfbits((v0 - mu) * rs * g[t]       + be[t]);
  orow[t + 256] = f2bfbits((v1 - mu) * rs * g[t + 256] + be[t + 256]);
  orow[t + 512] = f2bfbits((v2 - mu) * rs * g[t + 512] + be[t + 512]);
}

// ---------------- bf16 MFMA GEMM 128x128, ALL four GEMMs --------------------
// Round-0 structure; round-4 change: clobberless store_sync so the 2-deep
// uint4 register prefetch (p*/q*) stays in flight across the barriers
// instead of being drained by forced vmcnt(0) (round-0 hidden bug).
template <int EPI>
__global__ void __launch_bounds__(256, 3)
gemm_rs(const unsigned short* __restrict__ A,
        const unsigned short* __restrict__ Bt,
        const float* __restrict__ bias,
        const float* __restrict__ res,
        void* __restrict__ outv,
        int M, int N, int K) {
  __shared__ unsigned short lA[2][128 * 32];
  __shared__ unsigned short lB[2][128 * 32];
  int tid = threadIdx.x;
  int w = tid >> 6, lane = tid & 63;
  int id = blockIdx.x;
  int nn = N >> 7, bandM = (M >> 7) >> 3;
  int xcd = id & 7, s = id >> 3;
  int mt = xcd * bandM + s / nn;
  int nt = s - (s / nn) * nn;
  int m0 = mt * 128, n0 = nt * 128;
  int wm = (w >> 1) * 64, wn = (w & 1) * 64;
  f32x4 acc[4][4];
#pragma unroll
  for (int i = 0; i < 4; i++)
#pragma unroll
    for (int j = 0; j < 4; j++) acc[i][j] = (f32x4){0.f, 0.f, 0.f, 0.f};

  int sr = tid >> 2, sc = tid & 3;
  const unsigned short* gA = A + (size_t)(m0 + sr) * K + sc * 8;
  const unsigned short* gB = Bt + (size_t)(n0 + sr) * K + sc * 8;
  int wOff = sr * 64 + ((((sr >> 1) & 3) ^ sc) * 16);
  int fm = lane & 15, fg = lane >> 4;

  uint4 pA0, pA1, pB0, pB1;
  uint4 qA0, qA1, qB0, qB1;

  int nk = K >> 5;
  pA0 = *(const uint4*)(gA);
  pA1 = *(const uint4*)(gA + (size_t)64 * K);
  pB0 = *(const uint4*)(gB);
  pB1 = *(const uint4*)(gB + (size_t)64 * K);
  qA0 = *(const uint4*)(gA + 32);
  qA1 = *(const uint4*)(gA + (size_t)64 * K + 32);
  qB0 = *(const uint4*)(gB + 32);
  qB1 = *(const uint4*)(gB + (size_t)64 * K + 32);

  for (int k = 0; k < nk; k += 2) {
    {
      char* la = (char*)&lA[0][0];
      char* lb = (char*)&lB[0][0];
      *(uint4*)(la + wOff) = pA0;
      *(uint4*)(la + wOff + 4096) = pA1;
      *(uint4*)(lb + wOff) = pB0;
      *(uint4*)(lb + wOff + 4096) = pB1;
      if (k + 2 < nk) {
        int k0 = (k + 2) * 32;
        pA0 = *(const uint4*)(gA + k0);
        pA1 = *(const uint4*)(gA + (size_t)64 * K + k0);
        pB0 = *(const uint4*)(gB + k0);
        pB1 = *(const uint4*)(gB + (size_t)64 * K + k0);
      }
      store_sync();
      bf16x8 af[4], bfr[4];
#pragma unroll
      for (int i = 0; i < 4; i++) {
        int rr = wm + i * 16 + fm;
        af[i] = *(const bf16x8*)(la + rr * 64 + ((((rr >> 1) & 3) ^ fg) * 16));
      }
#pragma unroll
      for (int j = 0; j < 4; j++) {
        int rr = wn + j * 16 + fm;
        bfr[j] = *(const bf16x8*)(lb + rr * 64 + ((((rr >> 1) & 3) ^ fg) * 16));
      }
#pragma unroll
      for (int i = 0; i < 4; i++)
#pragma unroll
        for (int j = 0; j < 4; j++)
          acc[i][j] = __builtin_amdgcn_mfma_f32_16x16x32_bf16(af[i], bfr[j], acc[i][j], 0, 0, 0);
      store_sync();  // reads done before next sub-step's LDS overwrite
    }
    {
      char* la = (char*)&lA[1][0];
      char* lb = (char*)&lB[1][0];
      *(uint4*)(la + wOff) = qA0;
      *(uint4*)(la + wOff + 4096) = qA1;
      *(uint4*)(lb + wOff) = qB0;
      *(uint4*)(lb + wOff + 4096) = qB1;
      if (k + 3 < nk) {
        int k0 = (k + 3) * 32;
        qA0 = *(const uint4*)(gA + k0);
        qA1 = *(const uint4*)(gA + (size_t)64 * K + k0);
        qB0 = *(const uint4*)(gB + k0);
        qB1 = *(const uint4*)(gB + (size_t)64 * K + k0);
      }
      store_sync();
      bf16x8 af[4], bfr[4];
#pragma unroll
      for (int i = 0; i < 4; i++) {
        int rr = wm + i * 16 + fm;
        af[i] = *(const bf16x8*)(la + rr * 64 + ((((rr >> 1) & 3) ^ fg) * 16));
      }
#pragma unroll
      for (int j = 0; j < 4; j++) {
        int rr = wn + j * 16 + fm;
        bfr[j] = *(const bf16x8*)(lb + rr * 64 + ((((rr >> 1) & 3) ^ fg) * 16));
      }
#pragma unroll
      for (int i = 0; i < 4; i++)
#pragma unroll
        for (int j = 0; j < 4; j++)
          acc[i][j] = __builtin_amdgcn_mfma_f32_16x16x32_bf16(af[i], bfr[j], acc[i][j], 0, 0, 0);
      store_sync();
    }
  }

  int er = (lane >> 4) * 4, ec = lane & 15;
#pragma unroll
  for (int i = 0; i < 4; i++) {
#pragma unroll
    for (int j = 0; j < 4; j++) {
      int n = n0 + wn + j * 16 + ec;
      float bv = bias[n];
#pragma unroll
      for (int r = 0; r < 4; r++) {
        int m = m0 + wm + i * 16 + er + r;
        float v = acc[i][j][r] + bv;
        if (EPI == 1) {
          v += res[(size_t)m * N + n];
          ((float*)outv)[(size_t)m * N + n] = v;
        } else {
          if (EPI == 2) v = 0.5f * v * (1.0f + erff(v * 0.70710678118f));
          ((unsigned short*)outv)[(size_t)m * N + n] = f2bfbits(v);
        }
      }
    }
  }
}

// ---------------- ragged flash attention v4 ---------------------------------
// Clobberless sync: next-tile K/V register prefetch survives the barrier.
__global__ void attn_flash4(const unsigned short* __restrict__ qkv,
                            const unsigned short* __restrict__ vT,
                            const int* __restrict__ cu,
                            unsigned short* __restrict__ out, int M) {
  int id = blockIdx.x;
  int qc = id / 96;
  int bh = id - qc * 96;
  int b = bh / 12, h = bh - b * 12;
  int tok0 = cu[b];
  int len = cu[b + 1] - tok0;
  if (qc * 128 >= len) return;

  __shared__ unsigned short lK[2][64 * 64];
  __shared__ unsigned short lVT[2][64 * 64];

  int tid = threadIdx.x, w = tid >> 6, lane = tid & 63;
  int fm = lane & 15, fg = lane >> 4;
  int xm = fm & 7;
  int qbase = qc * 128 + w * 32;

  bf16x8 qf[2][2];
#pragma unroll
  for (int qs = 0; qs < 2; qs++)
#pragma unroll
    for (int kh = 0; kh < 2; kh++)
      qf[qs][kh] = *(const bf16x8*)(qkv + (size_t)(tok0 + qbase + qs * 16 + fm) * N_QKV +
                                    h * 64 + kh * 32 + fg * 8);

  f32x4 Oacc[2][4];
#pragma unroll
  for (int qs = 0; qs < 2; qs++)
#pragma unroll
    for (int dt = 0; dt < 4; dt++) Oacc[qs][dt] = (f32x4){0.f, 0.f, 0.f, 0.f};
  float lrow[2] = {0.f, 0.f};
  const float C2 = 0.18033688011112042f;  // log2(e)/sqrt(64)

  int sr = tid >> 3, sp = tid & 7, sl = sp ^ (sr & 7);
  const unsigned short* kg0 = qkv + D_MODEL + h * 64 + sl * 8;
  const unsigned short* vg0 = vT + (size_t)(h * 64 + sr) * M + tok0 + sl * 8;

  uint4 rk0, rk1, rv0, rv1;
  auto gload = [&](int kt) {
    rk0 = *(const uint4*)(kg0 + (size_t)(tok0 + kt + sr) * N_QKV);
    rk1 = *(const uint4*)(kg0 + (size_t)(tok0 + kt + sr + 32) * N_QKV);
    rv0 = *(const uint4*)(vg0 + kt);
    rv1 = *(const uint4*)(vg0 + (size_t)32 * M + kt);
  };

  int nkt = len >> 6;
  gload(0);
  for (int kt = 0; kt < nkt; kt++) {
    int cur = kt & 1;
    *(uint4*)((char*)&lK[cur][0] + tid * 16) = rk0;
    *(uint4*)((char*)&lK[cur][0] + tid * 16 + 4096) = rk1;
    *(uint4*)((char*)&lVT[cur][0] + tid * 16) = rv0;
    *(uint4*)((char*)&lVT[cur][0] + tid * 16 + 4096) = rv1;
    if (kt + 1 < nkt) gload((kt + 1) * 64);
    store_sync();

    f32x4 s[2][4];
#pragma unroll
    for (int qs = 0; qs < 2; qs++)
#pragma unroll
      for (int t = 0; t < 4; t++) s[qs][t] = (f32x4){0.f, 0.f, 0.f, 0.f};
#pragma unroll
    for (int t = 0; t < 4; t++) {
      bf16x8 kf0 = *(const bf16x8*)&lK[cur][(t * 16 + fm) * 64 + ((fg ^ xm) * 8)];
      bf16x8 kf1 = *(const bf16x8*)&lK[cur][(t * 16 + fm) * 64 + (((4 + fg) ^ xm) * 8)];
#pragma unroll
      for (int qs = 0; qs < 2; qs++) {
        s[qs][t] = __builtin_amdgcn_mfma_f32_16x16x32_bf16(kf0, qf[qs][0], s[qs][t], 0, 0, 0);
        s[qs][t] = __builtin_amdgcn_mfma_f32_16x16x32_bf16(kf1, qf[qs][1], s[qs][t], 0, 0, 0);
      }
    }

    union { bf16x8 v; unsigned u[4]; } af[2][2];
#pragma unroll
    for (int qs = 0; qs < 2; qs++) {
      float ssum = 0.f;
#pragma unroll
      for (int t = 0; t < 4; t++) {
#pragma unroll
        for (int r = 0; r < 4; r++) {
          float p = exp2f(s[qs][t][r] * C2);
          s[qs][t][r] = p;
          ssum += p;
        }
      }
      lrow[qs] += ssum;
      af[qs][0].u[0] = pk2(s[qs][0][0], s[qs][0][1]);
      af[qs][0].u[1] = pk2(s[qs][0][2], s[qs][0][3]);
      af[qs][0].u[2] = pk2(s[qs][1][0], s[qs][1][1]);
      af[qs][0].u[3] = pk2(s[qs][1][2], s[qs][1][3]);
      af[qs][1].u[0] = pk2(s[qs][2][0], s[qs][2][1]);
      af[qs][1].u[1] = pk2(s[qs][2][2], s[qs][2][3]);
      af[qs][1].u[2] = pk2(s[qs][3][0], s[qs][3][1]);
      af[qs][1].u[3] = pk2(s[qs][3][2], s[qs][3][3]);
    }

#pragma unroll
    for (int dt = 0; dt < 4; dt++) {
      bf16x8 vf0 = *(const bf16x8*)&lVT[cur][(dt * 16 + fm) * 64 + ((fg ^ xm) * 8)];
      bf16x8 vf1 = *(const bf16x8*)&lVT[cur][(dt * 16 + fm) * 64 + (((4 + fg) ^ xm) * 8)];
#pragma unroll
      for (int qs = 0; qs < 2; qs++) {
        Oacc[qs][dt] = __builtin_amdgcn_mfma_f32_16x16x32_bf16(af[qs][0].v, vf0, Oacc[qs][dt], 0, 0, 0);
        Oacc[qs][dt] = __builtin_amdgcn_mfma_f32_16x16x32_bf16(af[qs][1].v, vf1, Oacc[qs][dt], 0, 0, 0);
      }
    }
  }

#pragma unroll
  for (int qs = 0; qs < 2; qs++) {
    lrow[qs] += __shfl_xor(lrow[qs], 16, 64);
    lrow[qs] += __shfl_xor(lrow[qs], 32, 64);
    float inv = 1.0f / lrow[qs];
    float ir[4];
#pragma unroll
    for (int r = 0; r < 4; r++) ir[r] = __shfl(inv, fg * 4 + r, 64);
#pragma unroll
    for (int dt = 0; dt < 4; dt++)
#pragma unroll
      for (int r = 0; r < 4; r++)
        out[(size_t)(tok0 + qbase + qs * 16 + fg * 4 + r) * D_MODEL + h * 64 + dt * 16 + fm] =
            f2bfbits(Oacc[qs][dt][r] * ir[r]);
  }
}

extern "C" void kernel_launch(void* const* d_in, const int* in_sizes, int n_in,
                              void* d_out, int out_size, void* d_ws, size_t ws_size,
                              hipStream_t stream) {
  const float* x    = (const float*)d_in[0];
  const int* cu     = (const int*)d_in[1];
  const float* g1   = (const float*)d_in[2];
  const float* be1  = (const float*)d_in[3];
  const float* Wqkv = (const float*)d_in[4];
  const float* bqkv = (const float*)d_in[5];
  const float* Wo   = (const float*)d_in[6];
  const float* bo   = (const float*)d_in[7];
  const float* g2   = (const float*)d_in[8];
  const float* be2  = (const float*)d_in[9];
  const float* W1   = (const float*)d_in[10];
  const float* bfc1 = (const float*)d_in[11];
  const float* W2   = (const float*)d_in[12];
  const float* bfc2 = (const float*)d_in[13];
  float* out = (float*)d_out;
  int M = in_sizes[0] / D_MODEL;  // 6144

  unsigned short* WqkvT = (unsigned short*)d_ws;                       // 2304x768
  unsigned short* WoT   = WqkvT + 2304 * 768;                          // 768x768
  unsigned short* W1T   = WoT + 768 * 768;                             // 3072x768
  unsigned short* W2T   = W1T + 3072 * 768;                            // 768x3072
  unsigned short* bufA  = W2T + 768 * 3072;                            // M x 768 bf16
  float* x1             = (float*)(bufA + (size_t)M * D_MODEL);        // M x 768 f32
  unsigned short* qkvb  = (unsigned short*)(x1 + (size_t)M * D_MODEL); // M x 2304/3072 bf16
  unsigned short* vT = (unsigned short*)x1;  // overlaps x1 (dead before Wo-gemm)

  dim3 b32(32, 8);
  transpose_w<<<dim3(2304 / 32, 768 / 32), b32, 0, stream>>>(Wqkv, WqkvT, 768, 2304);
  transpose_w<<<dim3(768 / 32, 768 / 32), b32, 0, stream>>>(Wo, WoT, 768, 768);
  transpose_w<<<dim3(3072 / 32, 768 / 32), b32, 0, stream>>>(W1, W1T, 768, 3072);
  transpose_w<<<dim3(768 / 32, 3072 / 32), b32, 0, stream>>>(W2, W2T, 3072, 768);

  ln_bf16<<<M, 256, 0, stream>>>(x, g1, be1, bufA);
  gemm_rs<0><<<(2304 / 128) * (M / 128), 256, 0, stream>>>(bufA, WqkvT, bqkv, nullptr, qkvb, M, 2304, 768);
  transpose_v<<<dim3(M / 32, 768 / 32), b32, 0, stream>>>(qkvb, vT, M);
  attn_flash4<<<8 * 96, 256, 0, stream>>>(qkvb, vT, cu, bufA, M);
  gemm_rs<1><<<(768 / 128) * (M / 128), 256, 0, stream>>>(bufA, WoT, bo, x, x1, M, 768, 768);
  ln_bf16<<<M, 256, 0, stream>>>(x1, g2, be2, bufA);
  gemm_rs<2><<<(3072 / 128) * (M / 128), 256, 0, stream>>>(bufA, W1T, bfc1, nullptr, qkvb, M, 3072, 768);
  gemm_rs<1><<<(768 / 128) * (M / 128), 256, 0, stream>>>(qkvb, W2T, bfc2, x1, out, M, 768, 3072);
}

// Round 5
// 343.296 us; speedup vs baseline: 1.2003x; 1.0040x over previous
//
#include <hip/hip_runtime.h>
#include <hip/hip_bf16.h>
#include <stdint.h>
#include <string.h>

#define D_MODEL 768
#define H_HEADS 12
#define HD_ 64
#define N_QKV 2304

typedef __bf16 bf16x8 __attribute__((ext_vector_type(8)));
typedef float f32x4 __attribute__((ext_vector_type(4)));

__device__ __forceinline__ unsigned short f2bfbits(float f) {
  union { float f; unsigned u; } x; x.f = f;
  unsigned r = x.u + 0x7fffu + ((x.u >> 16) & 1u);
  return (unsigned short)(r >> 16);
}

// pack two non-negative floats to bf16 pair
__device__ __forceinline__ unsigned pk2(float a, float b) {
  union { float f; unsigned u; } x, y; x.f = a; y.f = b;
  return ((x.u + 0x8000u) >> 16) | ((y.u + 0x8000u) & 0xffff0000u);
}

// ---- sync idiom: NO "memory" clobber (a mayLoad/mayStore asm forces
// SIInsertWaitcnts to drain vmcnt -> kills in-flight global prefetch;
// proven by round-1->2 delta and round-0->4 gemm_rs delta 91.6->63.1us).
#define FENCE_() __builtin_amdgcn_sched_barrier(0)
__device__ __forceinline__ void store_sync() {
  FENCE_();
  asm volatile("s_waitcnt lgkmcnt(0)");   // own ds_writes drained pre-barrier
  FENCE_();
  __builtin_amdgcn_s_barrier();
  FENCE_();                               // keep following ds ops below barrier
}

// ---------------- weight transpose + fp32->bf16 ----------------
__global__ void transpose_w(const float* __restrict__ in, unsigned short* __restrict__ out,
                            int R, int C) {
  __shared__ float tile[32][33];
  int c0 = blockIdx.x * 32, r0 = blockIdx.y * 32;
  int tx = threadIdx.x, ty = threadIdx.y;
#pragma unroll
  for (int i = 0; i < 32; i += 8)
    tile[ty + i][tx] = in[(size_t)(r0 + ty + i) * C + c0 + tx];
  __syncthreads();
#pragma unroll
  for (int i = 0; i < 32; i += 8)
    out[(size_t)(c0 + ty + i) * R + r0 + tx] = f2bfbits(tile[tx][ty + i]);
}

// ---------------- V transpose with per-64-token key permute ----------------
__global__ void transpose_v(const unsigned short* __restrict__ qkv,
                            unsigned short* __restrict__ vT, int M) {
  __shared__ unsigned short tile[32][33];
  int t0 = blockIdx.x * 32, c0 = blockIdx.y * 32;
  int tx = threadIdx.x, ty = threadIdx.y;
#pragma unroll
  for (int i = 0; i < 32; i += 8)
    tile[ty + i][tx] = qkv[(size_t)(t0 + ty + i) * N_QKV + 1536 + c0 + tx];
  __syncthreads();
  int t = t0 + tx;
  int c = t & 63;
  int kp = ((c >> 5) << 5) | (((c >> 2) & 3) << 3) | (((c >> 4) & 1) << 2) | (c & 3);
  size_t col = (size_t)(t & ~63) + kp;
#pragma unroll
  for (int i = 0; i < 32; i += 8)
    vT[(size_t)(c0 + ty + i) * M + col] = tile[tx][ty + i];
}

// ---------------- layernorm -> bf16 ----------------
__global__ void ln_bf16(const float* __restrict__ x, const float* __restrict__ g,
                        const float* __restrict__ be, unsigned short* __restrict__ out) {
  int row = blockIdx.x;
  const float* xr = x + (size_t)row * D_MODEL;
  int t = threadIdx.x;
  float v0 = xr[t], v1 = xr[t + 256], v2 = xr[t + 512];
  float s = v0 + v1 + v2;
  float s2 = v0 * v0 + v1 * v1 + v2 * v2;
#pragma unroll
  for (int off = 32; off > 0; off >>= 1) {
    s += __shfl_down(s, off, 64);
    s2 += __shfl_down(s2, off, 64);
  }
  __shared__ float red[8];
  int w = t >> 6, lane = t & 63;
  if (lane == 0) { red[w] = s; red[w + 4] = s2; }
  __syncthreads();
  if (t == 0) {
    float a = red[0] + red[1] + red[2] + red[3];
    float b = red[4] + red[5] + red[6] + red[7];
    red[0] = a * (1.0f / 768.0f);
    red[4] = b * (1.0f / 768.0f);
  }
  __syncthreads();
  float mu = red[0];
  float var = red[4] - mu * mu;
  float rs = rsqrtf(var + 1e-6f);
  unsigned short* orow = out + (size_t)row * D_MODEL;
  orow[t]       = f2bfbits((v0 - mu) * rs * g[t]       + be[t]);
  orow[t + 256] = f2bfbits((v1 - mu) * rs * g[t + 256] + be[t + 256]);
  orow[t + 512] = f2bfbits((v2 - mu) * rs * g[t + 512] + be[t + 512]);
}

// ---------------- bf16 MFMA GEMM 128x128 (QKV, FC1) -------------------------
template <int EPI>
__global__ void __launch_bounds__(256, 3)
gemm_rs(const unsigned short* __restrict__ A,
        const unsigned short* __restrict__ Bt,
        const float* __restrict__ bias,
        const float* __restrict__ res,
        void* __restrict__ outv,
        int M, int N, int K) {
  __shared__ unsigned short lA[2][128 * 32];
  __shared__ unsigned short lB[2][128 * 32];
  int tid = threadIdx.x;
  int w = tid >> 6, lane = tid & 63;
  int id = blockIdx.x;
  int nn = N >> 7, bandM = (M >> 7) >> 3;
  int xcd = id & 7, s = id >> 3;
  int mt = xcd * bandM + s / nn;
  int nt = s - (s / nn) * nn;
  int m0 = mt * 128, n0 = nt * 128;
  int wm = (w >> 1) * 64, wn = (w & 1) * 64;
  f32x4 acc[4][4];
#pragma unroll
  for (int i = 0; i < 4; i++)
#pragma unroll
    for (int j = 0; j < 4; j++) acc[i][j] = (f32x4){0.f, 0.f, 0.f, 0.f};

  int sr = tid >> 2, sc = tid & 3;
  const unsigned short* gA = A + (size_t)(m0 + sr) * K + sc * 8;
  const unsigned short* gB = Bt + (size_t)(n0 + sr) * K + sc * 8;
  int wOff = sr * 64 + ((((sr >> 1) & 3) ^ sc) * 16);
  int fm = lane & 15, fg = lane >> 4;

  uint4 pA0, pA1, pB0, pB1;
  uint4 qA0, qA1, qB0, qB1;

  int nk = K >> 5;
  pA0 = *(const uint4*)(gA);
  pA1 = *(const uint4*)(gA + (size_t)64 * K);
  pB0 = *(const uint4*)(gB);
  pB1 = *(const uint4*)(gB + (size_t)64 * K);
  qA0 = *(const uint4*)(gA + 32);
  qA1 = *(const uint4*)(gA + (size_t)64 * K + 32);
  qB0 = *(const uint4*)(gB + 32);
  qB1 = *(const uint4*)(gB + (size_t)64 * K + 32);

  for (int k = 0; k < nk; k += 2) {
    {
      char* la = (char*)&lA[0][0];
      char* lb = (char*)&lB[0][0];
      *(uint4*)(la + wOff) = pA0;
      *(uint4*)(la + wOff + 4096) = pA1;
      *(uint4*)(lb + wOff) = pB0;
      *(uint4*)(lb + wOff + 4096) = pB1;
      if (k + 2 < nk) {
        int k0 = (k + 2) * 32;
        pA0 = *(const uint4*)(gA + k0);
        pA1 = *(const uint4*)(gA + (size_t)64 * K + k0);
        pB0 = *(const uint4*)(gB + k0);
        pB1 = *(const uint4*)(gB + (size_t)64 * K + k0);
      }
      store_sync();
      bf16x8 af[4], bfr[4];
#pragma unroll
      for (int i = 0; i < 4; i++) {
        int rr = wm + i * 16 + fm;
        af[i] = *(const bf16x8*)(la + rr * 64 + ((((rr >> 1) & 3) ^ fg) * 16));
      }
#pragma unroll
      for (int j = 0; j < 4; j++) {
        int rr = wn + j * 16 + fm;
        bfr[j] = *(const bf16x8*)(lb + rr * 64 + ((((rr >> 1) & 3) ^ fg) * 16));
      }
#pragma unroll
      for (int i = 0; i < 4; i++)
#pragma unroll
        for (int j = 0; j < 4; j++)
          acc[i][j] = __builtin_amdgcn_mfma_f32_16x16x32_bf16(af[i], bfr[j], acc[i][j], 0, 0, 0);
      store_sync();
    }
    {
      char* la = (char*)&lA[1][0];
      char* lb = (char*)&lB[1][0];
      *(uint4*)(la + wOff) = qA0;
      *(uint4*)(la + wOff + 4096) = qA1;
      *(uint4*)(lb + wOff) = qB0;
      *(uint4*)(lb + wOff + 4096) = qB1;
      if (k + 3 < nk) {
        int k0 = (k + 3) * 32;
        qA0 = *(const uint4*)(gA + k0);
        qA1 = *(const uint4*)(gA + (size_t)64 * K + k0);
        qB0 = *(const uint4*)(gB + k0);
        qB1 = *(const uint4*)(gB + (size_t)64 * K + k0);
      }
      store_sync();
      bf16x8 af[4], bfr[4];
#pragma unroll
      for (int i = 0; i < 4; i++) {
        int rr = wm + i * 16 + fm;
        af[i] = *(const bf16x8*)(la + rr * 64 + ((((rr >> 1) & 3) ^ fg) * 16));
      }
#pragma unroll
      for (int j = 0; j < 4; j++) {
        int rr = wn + j * 16 + fm;
        bfr[j] = *(const bf16x8*)(lb + rr * 64 + ((((rr >> 1) & 3) ^ fg) * 16));
      }
#pragma unroll
      for (int i = 0; i < 4; i++)
#pragma unroll
        for (int j = 0; j < 4; j++)
          acc[i][j] = __builtin_amdgcn_mfma_f32_16x16x32_bf16(af[i], bfr[j], acc[i][j], 0, 0, 0);
      store_sync();
    }
  }

  int er = (lane >> 4) * 4, ec = lane & 15;
#pragma unroll
  for (int i = 0; i < 4; i++) {
#pragma unroll
    for (int j = 0; j < 4; j++) {
      int n = n0 + wn + j * 16 + ec;
      float bv = bias[n];
#pragma unroll
      for (int r = 0; r < 4; r++) {
        int m = m0 + wm + i * 16 + er + r;
        float v = acc[i][j][r] + bv;
        if (EPI == 1) {
          v += res[(size_t)m * N + n];
          ((float*)outv)[(size_t)m * N + n] = v;
        } else {
          if (EPI == 2) v = 0.5f * v * (1.0f + erff(v * 0.70710678118f));
          ((unsigned short*)outv)[(size_t)m * N + n] = f2bfbits(v);
        }
      }
    }
  }
}

// ---------------- bf16 MFMA GEMM 128x64 (Wo, FC2: N=768) --------------------
// Occupancy fix for low-grid GEMMs: 288 blocks @128x128 = 1.125/CU (measured
// OccupancyPercent 8.2, all pipes idle -> latency-bound). 128x64 tiles ->
// 576 blocks, 24KB LDS, launch_bounds(256,4): all blocks co-resident.
template <int EPI>
__global__ void __launch_bounds__(256, 4)
gemm_n64(const unsigned short* __restrict__ A,
         const unsigned short* __restrict__ Bt,
         const float* __restrict__ bias,
         const float* __restrict__ res,
         void* __restrict__ outv,
         int M, int N, int K) {
  __shared__ unsigned short lA[2][128 * 32];
  __shared__ unsigned short lB[2][64 * 32];
  int tid = threadIdx.x;
  int w = tid >> 6, lane = tid & 63;
  int id = blockIdx.x;
  int nn = N >> 6, bandM = (M >> 7) >> 3;
  int xcd = id & 7, s = id >> 3;
  int mt = xcd * bandM + s / nn;
  int nt = s - (s / nn) * nn;
  int m0 = mt * 128, n0 = nt * 64;
  int wm = w * 32;
  f32x4 acc[2][4];
#pragma unroll
  for (int i = 0; i < 2; i++)
#pragma unroll
    for (int j = 0; j < 4; j++) acc[i][j] = (f32x4){0.f, 0.f, 0.f, 0.f};

  int sr = tid >> 2, sc = tid & 3;
  const unsigned short* gA = A + (size_t)(m0 + sr) * K + sc * 8;
  const unsigned short* gB = Bt + (size_t)(n0 + sr) * K + sc * 8;  // sr<64: whole B tile
  int wOff = sr * 64 + ((((sr >> 1) & 3) ^ sc) * 16);
  int fm = lane & 15, fg = lane >> 4;

  uint4 pA0, pA1, pB0;
  uint4 qA0, qA1, qB0;

  int nk = K >> 5;
  pA0 = *(const uint4*)(gA);
  pA1 = *(const uint4*)(gA + (size_t)64 * K);
  pB0 = *(const uint4*)(gB);
  qA0 = *(const uint4*)(gA + 32);
  qA1 = *(const uint4*)(gA + (size_t)64 * K + 32);
  qB0 = *(const uint4*)(gB + 32);

  for (int k = 0; k < nk; k += 2) {
    {
      char* la = (char*)&lA[0][0];
      char* lb = (char*)&lB[0][0];
      *(uint4*)(la + wOff) = pA0;
      *(uint4*)(la + wOff + 4096) = pA1;
      *(uint4*)(lb + wOff) = pB0;
      if (k + 2 < nk) {
        int k0 = (k + 2) * 32;
        pA0 = *(const uint4*)(gA + k0);
        pA1 = *(const uint4*)(gA + (size_t)64 * K + k0);
        pB0 = *(const uint4*)(gB + k0);
      }
      store_sync();
      bf16x8 af[2], bfr[4];
#pragma unroll
      for (int i = 0; i < 2; i++) {
        int rr = wm + i * 16 + fm;
        af[i] = *(const bf16x8*)(la + rr * 64 + ((((rr >> 1) & 3) ^ fg) * 16));
      }
#pragma unroll
      for (int j = 0; j < 4; j++) {
        int rr = j * 16 + fm;
        bfr[j] = *(const bf16x8*)(lb + rr * 64 + ((((rr >> 1) & 3) ^ fg) * 16));
      }
#pragma unroll
      for (int i = 0; i < 2; i++)
#pragma unroll
        for (int j = 0; j < 4; j++)
          acc[i][j] = __builtin_amdgcn_mfma_f32_16x16x32_bf16(af[i], bfr[j], acc[i][j], 0, 0, 0);
      store_sync();
    }
    {
      char* la = (char*)&lA[1][0];
      char* lb = (char*)&lB[1][0];
      *(uint4*)(la + wOff) = qA0;
      *(uint4*)(la + wOff + 4096) = qA1;
      *(uint4*)(lb + wOff) = qB0;
      if (k + 3 < nk) {
        int k0 = (k + 3) * 32;
        qA0 = *(const uint4*)(gA + k0);
        qA1 = *(const uint4*)(gA + (size_t)64 * K + k0);
        qB0 = *(const uint4*)(gB + k0);
      }
      store_sync();
      bf16x8 af[2], bfr[4];
#pragma unroll
      for (int i = 0; i < 2; i++) {
        int rr = wm + i * 16 + fm;
        af[i] = *(const bf16x8*)(la + rr * 64 + ((((rr >> 1) & 3) ^ fg) * 16));
      }
#pragma unroll
      for (int j = 0; j < 4; j++) {
        int rr = j * 16 + fm;
        bfr[j] = *(const bf16x8*)(lb + rr * 64 + ((((rr >> 1) & 3) ^ fg) * 16));
      }
#pragma unroll
      for (int i = 0; i < 2; i++)
#pragma unroll
        for (int j = 0; j < 4; j++)
          acc[i][j] = __builtin_amdgcn_mfma_f32_16x16x32_bf16(af[i], bfr[j], acc[i][j], 0, 0, 0);
      store_sync();
    }
  }

  int er = (lane >> 4) * 4, ec = lane & 15;
#pragma unroll
  for (int i = 0; i < 2; i++) {
#pragma unroll
    for (int j = 0; j < 4; j++) {
      int n = n0 + j * 16 + ec;
      float bv = bias[n];
#pragma unroll
      for (int r = 0; r < 4; r++) {
        int m = m0 + wm + i * 16 + er + r;
        float v = acc[i][j][r] + bv;
        if (EPI == 1) {
          v += res[(size_t)m * N + n];
          ((float*)outv)[(size_t)m * N + n] = v;
        } else {
          if (EPI == 2) v = 0.5f * v * (1.0f + erff(v * 0.70710678118f));
          ((unsigned short*)outv)[(size_t)m * N + n] = f2bfbits(v);
        }
      }
    }
  }
}

// ---------------- ragged flash attention v4 ---------------------------------
__global__ void attn_flash4(const unsigned short* __restrict__ qkv,
                            const unsigned short* __restrict__ vT,
                            const int* __restrict__ cu,
                            unsigned short* __restrict__ out, int M) {
  int id = blockIdx.x;
  int qc = id / 96;
  int bh = id - qc * 96;
  int b = bh / 12, h = bh - b * 12;
  int tok0 = cu[b];
  int len = cu[b + 1] - tok0;
  if (qc * 128 >= len) return;

  __shared__ unsigned short lK[2][64 * 64];
  __shared__ unsigned short lVT[2][64 * 64];

  int tid = threadIdx.x, w = tid >> 6, lane = tid & 63;
  int fm = lane & 15, fg = lane >> 4;
  int xm = fm & 7;
  int qbase = qc * 128 + w * 32;

  bf16x8 qf[2][2];
#pragma unroll
  for (int qs = 0; qs < 2; qs++)
#pragma unroll
    for (int kh = 0; kh < 2; kh++)
      qf[qs][kh] = *(const bf16x8*)(qkv + (size_t)(tok0 + qbase + qs * 16 + fm) * N_QKV +
                                    h * 64 + kh * 32 + fg * 8);

  f32x4 Oacc[2][4];
#pragma unroll
  for (int qs = 0; qs < 2; qs++)
#pragma unroll
    for (int dt = 0; dt < 4; dt++) Oacc[qs][dt] = (f32x4){0.f, 0.f, 0.f, 0.f};
  float lrow[2] = {0.f, 0.f};
  const float C2 = 0.18033688011112042f;  // log2(e)/sqrt(64)

  int sr = tid >> 3, sp = tid & 7, sl = sp ^ (sr & 7);
  const unsigned short* kg0 = qkv + D_MODEL + h * 64 + sl * 8;
  const unsigned short* vg0 = vT + (size_t)(h * 64 + sr) * M + tok0 + sl * 8;

  uint4 rk0, rk1, rv0, rv1;
  auto gload = [&](int kt) {
    rk0 = *(const uint4*)(kg0 + (size_t)(tok0 + kt + sr) * N_QKV);
    rk1 = *(const uint4*)(kg0 + (size_t)(tok0 + kt + sr + 32) * N_QKV);
    rv0 = *(const uint4*)(vg0 + kt);
    rv1 = *(const uint4*)(vg0 + (size_t)32 * M + kt);
  };

  int nkt = len >> 6;
  gload(0);
  for (int kt = 0; kt < nkt; kt++) {
    int cur = kt & 1;
    *(uint4*)((char*)&lK[cur][0] + tid * 16) = rk0;
    *(uint4*)((char*)&lK[cur][0] + tid * 16 + 4096) = rk1;
    *(uint4*)((char*)&lVT[cur][0] + tid * 16) = rv0;
    *(uint4*)((char*)&lVT[cur][0] + tid * 16 + 4096) = rv1;
    if (kt + 1 < nkt) gload((kt + 1) * 64);
    store_sync();

    f32x4 s[2][4];
#pragma unroll
    for (int qs = 0; qs < 2; qs++)
#pragma unroll
      for (int t = 0; t < 4; t++) s[qs][t] = (f32x4){0.f, 0.f, 0.f, 0.f};
#pragma unroll
    for (int t = 0; t < 4; t++) {
      bf16x8 kf0 = *(const bf16x8*)&lK[cur][(t * 16 + fm) * 64 + ((fg ^ xm) * 8)];
      bf16x8 kf1 = *(const bf16x8*)&lK[cur][(t * 16 + fm) * 64 + (((4 + fg) ^ xm) * 8)];
#pragma unroll
      for (int qs = 0; qs < 2; qs++) {
        s[qs][t] = __builtin_amdgcn_mfma_f32_16x16x32_bf16(kf0, qf[qs][0], s[qs][t], 0, 0, 0);
        s[qs][t] = __builtin_amdgcn_mfma_f32_16x16x32_bf16(kf1, qf[qs][1], s[qs][t], 0, 0, 0);
      }
    }

    union { bf16x8 v; unsigned u[4]; } af[2][2];
#pragma unroll
    for (int qs = 0; qs < 2; qs++) {
      float ssum = 0.f;
#pragma unroll
      for (int t = 0; t < 4; t++) {
#pragma unroll
        for (int r = 0; r < 4; r++) {
          float p = exp2f(s[qs][t][r] * C2);
          s[qs][t][r] = p;
          ssum += p;
        }
      }
      lrow[qs] += ssum;
      af[qs][0].u[0] = pk2(s[qs][0][0], s[qs][0][1]);
      af[qs][0].u[1] = pk2(s[qs][0][2], s[qs][0][3]);
      af[qs][0].u[2] = pk2(s[qs][1][0], s[qs][1][1]);
      af[qs][0].u[3] = pk2(s[qs][1][2], s[qs][1][3]);
      af[qs][1].u[0] = pk2(s[qs][2][0], s[qs][2][1]);
      af[qs][1].u[1] = pk2(s[qs][2][2], s[qs][2][3]);
      af[qs][1].u[2] = pk2(s[qs][3][0], s[qs][3][1]);
      af[qs][1].u[3] = pk2(s[qs][3][2], s[qs][3][3]);
    }

#pragma unroll
    for (int dt = 0; dt < 4; dt++) {
      bf16x8 vf0 = *(const bf16x8*)&lVT[cur][(dt * 16 + fm) * 64 + ((fg ^ xm) * 8)];
      bf16x8 vf1 = *(const bf16x8*)&lVT[cur][(dt * 16 + fm) * 64 + (((4 + fg) ^ xm) * 8)];
#pragma unroll
      for (int qs = 0; qs < 2; qs++) {
        Oacc[qs][dt] = __builtin_amdgcn_mfma_f32_16x16x32_bf16(af[qs][0].v, vf0, Oacc[qs][dt], 0, 0, 0);
        Oacc[qs][dt] = __builtin_amdgcn_mfma_f32_16x16x32_bf16(af[qs][1].v, vf1, Oacc[qs][dt], 0, 0, 0);
      }
    }
  }

#pragma unroll
  for (int qs = 0; qs < 2; qs++) {
    lrow[qs] += __shfl_xor(lrow[qs], 16, 64);
    lrow[qs] += __shfl_xor(lrow[qs], 32, 64);
    float inv = 1.0f / lrow[qs];
    float ir[4];
#pragma unroll
    for (int r = 0; r < 4; r++) ir[r] = __shfl(inv, fg * 4 + r, 64);
#pragma unroll
    for (int dt = 0; dt < 4; dt++)
#pragma unroll
      for (int r = 0; r < 4; r++)
        out[(size_t)(tok0 + qbase + qs * 16 + fg * 4 + r) * D_MODEL + h * 64 + dt * 16 + fm] =
            f2bfbits(Oacc[qs][dt][r] * ir[r]);
  }
}

extern "C" void kernel_launch(void* const* d_in, const int* in_sizes, int n_in,
                              void* d_out, int out_size, void* d_ws, size_t ws_size,
                              hipStream_t stream) {
  const float* x    = (const float*)d_in[0];
  const int* cu     = (const int*)d_in[1];
  const float* g1   = (const float*)d_in[2];
  const float* be1  = (const float*)d_in[3];
  const float* Wqkv = (const float*)d_in[4];
  const float* bqkv = (const float*)d_in[5];
  const float* Wo   = (const float*)d_in[6];
  const float* bo   = (const float*)d_in[7];
  const float* g2   = (const float*)d_in[8];
  const float* be2  = (const float*)d_in[9];
  const float* W1   = (const float*)d_in[10];
  const float* bfc1 = (const float*)d_in[11];
  const float* W2   = (const float*)d_in[12];
  const float* bfc2 = (const float*)d_in[13];
  float* out = (float*)d_out;
  int M = in_sizes[0] / D_MODEL;  // 6144

  unsigned short* WqkvT = (unsigned short*)d_ws;                       // 2304x768
  unsigned short* WoT   = WqkvT + 2304 * 768;                          // 768x768
  unsigned short* W1T   = WoT + 768 * 768;                             // 3072x768
  unsigned short* W2T   = W1T + 3072 * 768;                            // 768x3072
  unsigned short* bufA  = W2T + 768 * 3072;                            // M x 768 bf16
  float* x1             = (float*)(bufA + (size_t)M * D_MODEL);        // M x 768 f32
  unsigned short* qkvb  = (unsigned short*)(x1 + (size_t)M * D_MODEL); // M x 2304/3072 bf16
  unsigned short* vT = (unsigned short*)x1;  // overlaps x1 (dead before Wo-gemm)

  dim3 b32(32, 8);
  transpose_w<<<dim3(2304 / 32, 768 / 32), b32, 0, stream>>>(Wqkv, WqkvT, 768, 2304);
  transpose_w<<<dim3(768 / 32, 768 / 32), b32, 0, stream>>>(Wo, WoT, 768, 768);
  transpose_w<<<dim3(3072 / 32, 768 / 32), b32, 0, stream>>>(W1, W1T, 768, 3072);
  transpose_w<<<dim3(768 / 32, 3072 / 32), b32, 0, stream>>>(W2, W2T, 3072, 768);

  ln_bf16<<<M, 256, 0, stream>>>(x, g1, be1, bufA);
  gemm_rs<0><<<(2304 / 128) * (M / 128), 256, 0, stream>>>(bufA, WqkvT, bqkv, nullptr, qkvb, M, 2304, 768);
  transpose_v<<<dim3(M / 32, 768 / 32), b32, 0, stream>>>(qkvb, vT, M);
  attn_flash4<<<8 * 96, 256, 0, stream>>>(qkvb, vT, cu, bufA, M);
  gemm_n64<1><<<(768 / 64) * (M / 128), 256, 0, stream>>>(bufA, WoT, bo, x, x1, M, 768, 768);
  ln_bf16<<<M, 256, 0, stream>>>(x1, g2, be2, bufA);
  gemm_rs<2><<<(3072 / 128) * (M / 128), 256, 0, stream>>>(bufA, W1T, bfc1, nullptr, qkvb, M, 3072, 768);
  gemm_n64<1><<<(768 / 64) * (M / 128), 256, 0, stream>>>(qkvb, W2T, bfc2, x1, out, M, 768, 3072);
}